// Round 3
// baseline (549.442 us; speedup 1.0000x reference)
//
#include <hip/hip_runtime.h>

#define NTOK 100352   // 8*112*112
#define NPB  12544    // tokens per batch (112*112)
#define CH   256

typedef unsigned short u16;
typedef float f32x4 __attribute__((ext_vector_type(4)));
typedef short bfrag __attribute__((ext_vector_type(8)));   // 8 bf16 = 4 VGPRs

static __device__ __forceinline__ u16 f2bf(float f) {
    union { float f; unsigned u; } v; v.f = f;
    unsigned r = v.u + 0x7FFFu + ((v.u >> 16) & 1u);   // RNE
    return (u16)(r >> 16);
}
static __device__ __forceinline__ float bf2f(u16 h) {
    union { unsigned u; float f; } v; v.u = ((unsigned)h) << 16;
    return v.f;
}
static __device__ __forceinline__ unsigned pk2(float a, float b) {
    return (unsigned)f2bf(a) | ((unsigned)f2bf(b) << 16);
}

// ---------------- K0: weight prep (fp32 -> bf16, fold q scale) ----------------
__global__ __launch_bounds__(256)
void swa_prep(const float* __restrict__ wq, const float* __restrict__ wk,
              const float* __restrict__ wv, const float* __restrict__ wm,
              u16* __restrict__ wcat, u16* __restrict__ wmb)
{
    int i0 = blockIdx.x * 256 + threadIdx.x;
    int stride = gridDim.x * 256;
    for (int i = i0; i < 768 * 256; i += stride) {
        int r = i >> 8, c = i & 255;
        float v;
        if (r < 256)      v = wq[r * 256 + c] * 0.0625f;      // fold d^-0.5 = 1/16
        else if (r < 512) v = wk[(r - 256) * 256 + c];
        else              v = wv[(r - 512) * 256 + c];
        wcat[i] = f2bf(v);
    }
    for (int i = i0; i < 256 * 256; i += stride) wmb[i] = f2bf(wm[i]);
}

// ---------------- K1: roll + LN + QKV projection ----------------
// 1176 blocks = 392 strips x 3 sections; 256 thr; strip = 256 tokens, 8 iters x 32.
// MFMA with A=weights: D row=channel -> 4 consecutive ch/lane -> dwordx2 stores.
// Double-buffered LDS tile: 1 barrier/iter.
__global__ __launch_bounds__(256, 3)
void swa_qkv3(const float* __restrict__ x,
              const float* __restrict__ ln_g, const float* __restrict__ ln_b,
              const u16* __restrict__ wcat,
              const float* __restrict__ bq, const float* __restrict__ bk,
              const float* __restrict__ bv,
              u16* __restrict__ qbuf, u16* __restrict__ kbuf, u16* __restrict__ vbuf)
{
    __shared__ u16   xs[2][32 * 256];                 // 32 KB, chunk-XOR swizzled
    __shared__ float lng[256], lnb[256];
    __shared__ float __attribute__((aligned(16))) knorm[2][32][4];

    const int tid  = threadIdx.x;
    const int lane = tid & 63;
    const int wid  = tid >> 6;
    const int r16  = lane & 15;
    const int g4   = lane >> 4;

    const int swz   = (blockIdx.x & 7) * 147 + (blockIdx.x >> 3);   // XCD-bijective
    const int sec   = swz % 3;                        // 0=q 1=k 2=v
    const int strip = swz / 3;
    const int tok0  = strip * 256;

    lng[tid] = ln_g[tid]; lnb[tid] = ln_b[tid];

    const float* bsec = (sec == 0) ? bq : (sec == 1) ? bk : bv;
    u16*         outp = (sec == 0) ? qbuf : (sec == 1) ? kbuf : vbuf;
    const float  bscale = (sec == 0) ? 0.0625f : 1.0f;

    const int chb = wid * 64 + g4 * 4;                // lane's channel base (+ct*16)
    f32x4 bias4[4];
    #pragma unroll
    for (int ct = 0; ct < 4; ++ct) {
        f32x4 b = *reinterpret_cast<const f32x4*>(bsec + chb + ct * 16);
        bias4[ct][0] = b[0] * bscale; bias4[ct][1] = b[1] * bscale;
        bias4[ct][2] = b[2] * bscale; bias4[ct][3] = b[3] * bscale;
    }
    const u16* wbase = wcat + (size_t)(sec * 256 + wid * 64 + r16) * CH + g4 * 8;

    // loaders: 8 threads per token row
    const int r   = tid >> 3;
    const int sub = tid & 7;
    f32x4 xv[8];

    auto load_x = [&](int it) {
        int tok = tok0 + it * 32 + r;
        int b_  = tok / NPB;
        int rem = tok - b_ * NPB;
        int hs  = rem / 112, wsd = rem - hs * 112;
        int h0  = hs - 3 + ((hs < 3) ? 112 : 0);      // shifted read
        int w0  = wsd - 3 + ((wsd < 3) ? 112 : 0);
        const float* rowp = x + (size_t)(b_ * NPB + h0 * 112 + w0) * CH;
        #pragma unroll
        for (int j = 0; j < 8; ++j)
            xv[j] = *reinterpret_cast<const f32x4*>(rowp + (sub + 8 * j) * 4);
    };
    auto stage = [&](int buf) {
        float s = 0.f, sq = 0.f;
        #pragma unroll
        for (int j = 0; j < 8; ++j) {
            s  += xv[j][0] + xv[j][1] + xv[j][2] + xv[j][3];
            sq += xv[j][0]*xv[j][0] + xv[j][1]*xv[j][1] + xv[j][2]*xv[j][2] + xv[j][3]*xv[j][3];
        }
        s += __shfl_xor(s, 1); sq += __shfl_xor(sq, 1);
        s += __shfl_xor(s, 2); sq += __shfl_xor(sq, 2);
        s += __shfl_xor(s, 4); sq += __shfl_xor(sq, 4);
        float mu  = s * (1.0f / 256.0f);
        float var = sq * (1.0f / 256.0f) - mu * mu;
        float inv = 1.0f / sqrtf(var + 1e-5f);
        char* dst = (char*)xs[buf];
        #pragma unroll
        for (int j = 0; j < 8; ++j) {
            int cf = sub + 8 * j;
            f32x4 g = *reinterpret_cast<const f32x4*>(&lng[cf * 4]);
            f32x4 b = *reinterpret_cast<const f32x4*>(&lnb[cf * 4]);
            uint2 p;
            p.x = pk2((xv[j][0] - mu) * inv * g[0] + b[0], (xv[j][1] - mu) * inv * g[1] + b[1]);
            p.y = pk2((xv[j][2] - mu) * inv * g[2] + b[2], (xv[j][3] - mu) * inv * g[3] + b[3]);
            int off = r * 512 + ((((cf >> 1)) ^ (r & 7)) << 4) + (cf & 1) * 8;
            *reinterpret_cast<uint2*>(dst + off) = p;
        }
    };

    load_x(0);
    __syncthreads();            // lng/lnb visible
    stage(0);
    load_x(1);
    __syncthreads();            // xs[0] staged

    for (int t = 0; t < 8; ++t) {
        const int b = t & 1;
        const char* xbase = (const char*)xs[b];

        f32x4 acc[4][2];
        #pragma unroll
        for (int ct = 0; ct < 4; ++ct) { acc[ct][0] = (f32x4)0.f; acc[ct][1] = (f32x4)0.f; }
        #pragma unroll
        for (int kk = 0; kk < 8; ++kk) {
            int csw = ((kk * 4 + g4) ^ (r16 & 7)) << 4;
            bfrag b0 = *reinterpret_cast<const bfrag*>(xbase + r16 * 512 + csw);
            bfrag b1 = *reinterpret_cast<const bfrag*>(xbase + (16 + r16) * 512 + csw);
            #pragma unroll
            for (int ct = 0; ct < 4; ++ct) {
                bfrag wf = *reinterpret_cast<const bfrag*>(wbase + (size_t)ct * 16 * CH + kk * 32);
                acc[ct][0] = __builtin_amdgcn_mfma_f32_16x16x32_bf16(wf, b0, acc[ct][0], 0, 0, 0);
                acc[ct][1] = __builtin_amdgcn_mfma_f32_16x16x32_bf16(wf, b1, acc[ct][1], 0, 0, 0);
            }
        }
        #pragma unroll
        for (int ct = 0; ct < 4; ++ct)
            #pragma unroll
            for (int rt = 0; rt < 2; ++rt)
                #pragma unroll
                for (int rr = 0; rr < 4; ++rr) acc[ct][rt][rr] += bias4[ct][rr];

        if (sec == 1) {                               // k-norm partials (pre-barrier)
            float p0 = 0.f, p1 = 0.f;
            #pragma unroll
            for (int ct = 0; ct < 4; ++ct)
                #pragma unroll
                for (int rr = 0; rr < 4; ++rr) {
                    p0 += acc[ct][0][rr] * acc[ct][0][rr];
                    p1 += acc[ct][1][rr] * acc[ct][1][rr];
                }
            p0 += __shfl_xor(p0, 16); p0 += __shfl_xor(p0, 32);
            p1 += __shfl_xor(p1, 16); p1 += __shfl_xor(p1, 32);
            if (g4 == 0) { knorm[b][r16][wid] = p0; knorm[b][16 + r16][wid] = p1; }
        }

        if (t < 7) stage(b ^ 1);                      // consumes xv (tile t+1)
        if (t < 6) load_x(t + 2);                     // refill xv
        __syncthreads();                              // the iter's single barrier

        float invn[2] = {1.f, 1.f};
        if (sec == 1) {
            #pragma unroll
            for (int rt = 0; rt < 2; ++rt) {
                f32x4 k4 = *reinterpret_cast<const f32x4*>(knorm[b][rt * 16 + r16]);
                invn[rt] = 1.0f / fmaxf(sqrtf(k4[0] + k4[1] + k4[2] + k4[3]), 1e-12f);
            }
        }
        #pragma unroll
        for (int ct = 0; ct < 4; ++ct)
            #pragma unroll
            for (int rt = 0; rt < 2; ++rt) {
                int tok = tok0 + t * 32 + rt * 16 + r16;
                uint2 p;
                p.x = pk2(acc[ct][rt][0] * invn[rt], acc[ct][rt][1] * invn[rt]);
                p.y = pk2(acc[ct][rt][2] * invn[rt], acc[ct][rt][3] * invn[rt]);
                *reinterpret_cast<uint2*>(outp + (size_t)tok * CH + chb + ct * 16) = p;
            }
    }
}

// ---------------- K2: local attention, one wave per 7-token window ----------------
__global__ __launch_bounds__(256)
void swa_attn(const u16* qbuf, const u16* kbuf, const u16* vbuf, u16* obuf)
{
    __shared__ float plds[4][16][17];
    const int tid  = threadIdx.x;
    const int lane = tid & 63;
    const int wid  = tid >> 6;
    const int win  = blockIdx.x * 4 + wid;
    const int iw   = win % 1792;
    const int base = win * 7;
    const int r16  = lane & 15;
    const int g4   = lane >> 4;

    int qrow = base + r16; if (qrow > NTOK - 1) qrow = NTOK - 1;
    int krow = base - 7 + r16; if (krow < 0) krow = 0;
    const u16* qp = qbuf + (size_t)qrow * CH + g4 * 8;
    const u16* kp = kbuf + (size_t)krow * CH + g4 * 8;

    f32x4 s4 = {0.f, 0.f, 0.f, 0.f};
    #pragma unroll
    for (int kk = 0; kk < 8; ++kk) {
        bfrag a = *reinterpret_cast<const bfrag*>(qp + kk * 32);
        bfrag b = *reinterpret_cast<const bfrag*>(kp + kk * 32);
        s4 = __builtin_amdgcn_mfma_f32_16x16x32_bf16(a, b, s4, 0, 0, 0);
    }

    const int  j     = r16;
    const bool first = (iw == 0);
    #pragma unroll
    for (int rr = 0; rr < 4; ++rr) {
        int i = g4 * 4 + rr;
        float s = s4[rr];
        if (j == i + 7) s = -5.0e4f;
        if (j > i + 7 || j >= 14 || (first && j < 7)) s = -3.0e38f;
        s4[rr] = s;
    }
    f32x4 mx = s4;
    #pragma unroll
    for (int off = 8; off; off >>= 1) {
        #pragma unroll
        for (int rr = 0; rr < 4; ++rr) mx[rr] = fmaxf(mx[rr], __shfl_xor(mx[rr], off));
    }
    f32x4 p;
    #pragma unroll
    for (int rr = 0; rr < 4; ++rr) p[rr] = __expf(s4[rr] - mx[rr]);
    f32x4 sm = p;
    #pragma unroll
    for (int off = 8; off; off >>= 1) {
        #pragma unroll
        for (int rr = 0; rr < 4; ++rr) sm[rr] += __shfl_xor(sm[rr], off);
    }
    #pragma unroll
    for (int rr = 0; rr < 4; ++rr) plds[wid][g4 * 4 + rr][j] = p[rr] / sm[rr];
    __syncthreads();

    f32x4 zero4 = {0.f, 0.f, 0.f, 0.f};
    f32x4 oa[7];
    #pragma unroll
    for (int i = 0; i < 7; ++i) oa[i] = zero4;
    for (int jj = 0; jj < 14; ++jj) {
        int vrow = base - 7 + jj;
        if (vrow < 0) vrow = 0;
        ushort4 vr = *reinterpret_cast<const ushort4*>(vbuf + (size_t)vrow * CH + lane * 4);
        f32x4 vvv; vvv[0] = bf2f(vr.x); vvv[1] = bf2f(vr.y); vvv[2] = bf2f(vr.z); vvv[3] = bf2f(vr.w);
        #pragma unroll
        for (int i = 0; i < 7; ++i) {
            float pp = plds[wid][i][jj];
            oa[i][0] += pp * vvv[0]; oa[i][1] += pp * vvv[1];
            oa[i][2] += pp * vvv[2]; oa[i][3] += pp * vvv[3];
        }
    }
    #pragma unroll
    for (int i = 0; i < 7; ++i) {
        ushort4 o; o.x = f2bf(oa[i][0]); o.y = f2bf(oa[i][1]); o.z = f2bf(oa[i][2]); o.w = f2bf(oa[i][3]);
        *reinterpret_cast<ushort4*>(obuf + (size_t)(base + i) * CH + lane * 4) = o;
    }
}

// ---------------- K3: unshift + residual + LN + MLP(GELU) + add ----------------
// 784 blocks x 128 tokens (4 iters x 32). Same skeleton as K1; rsd staged bf16.
__global__ __launch_bounds__(256, 3)
void swa_mlp3(const float* __restrict__ x, const u16* __restrict__ abuf,
              const float* __restrict__ ln_g, const float* __restrict__ ln_b,
              const u16* __restrict__ wmb, const float* __restrict__ mbias,
              float* __restrict__ out)
{
    __shared__ u16   xs[2][32 * 256];                 // 32 KB
    __shared__ u16   rsdl[32 * 256];                  // 16 KB, bf16 residual
    __shared__ float lng[256], lnb[256];

    const int tid  = threadIdx.x;
    const int lane = tid & 63;
    const int wid  = tid >> 6;
    const int r16  = lane & 15;
    const int g4   = lane >> 4;

    const int swz  = (blockIdx.x & 7) * 98 + (blockIdx.x >> 3);
    const int tok0 = swz * 128;

    lng[tid] = ln_g[tid]; lnb[tid] = ln_b[tid];

    const int chb = wid * 64 + g4 * 4;
    f32x4 bias4[4];
    #pragma unroll
    for (int ct = 0; ct < 4; ++ct)
        bias4[ct] = *reinterpret_cast<const f32x4*>(mbias + chb + ct * 16);
    const u16* wbase = wmb + (size_t)(wid * 64 + r16) * CH + g4 * 8;

    const int r   = tid >> 3;
    const int sub = tid & 7;
    f32x4   xv[8];
    ushort4 av[8];

    auto load_res = [&](int it) {
        int tok = tok0 + it * 32 + r;
        int b_  = tok / NPB, rem = tok - b_ * NPB;
        int h = rem / 112, w = rem - h * 112;
        int hs = h + 3;  if (hs >= 112) hs -= 112;    // unshift: attn[(h+3)%112][(w+3)%112]
        int ws_ = w + 3; if (ws_ >= 112) ws_ -= 112;
        const u16*   arow = abuf + (size_t)(b_ * NPB + hs * 112 + ws_) * CH;
        const float* xrow = x + (size_t)tok * CH;
        #pragma unroll
        for (int j = 0; j < 8; ++j) {
            xv[j] = *reinterpret_cast<const f32x4*>(xrow + (sub + 8 * j) * 4);
            av[j] = *reinterpret_cast<const ushort4*>(arow + (sub + 8 * j) * 4);
        }
    };
    auto stage = [&](int buf) {
        f32x4 rv[8];
        float s = 0.f, sq = 0.f;
        #pragma unroll
        for (int j = 0; j < 8; ++j) {
            rv[j][0] = xv[j][0] + bf2f(av[j].x); rv[j][1] = xv[j][1] + bf2f(av[j].y);
            rv[j][2] = xv[j][2] + bf2f(av[j].z); rv[j][3] = xv[j][3] + bf2f(av[j].w);
            s  += rv[j][0] + rv[j][1] + rv[j][2] + rv[j][3];
            sq += rv[j][0]*rv[j][0] + rv[j][1]*rv[j][1] + rv[j][2]*rv[j][2] + rv[j][3]*rv[j][3];
        }
        s += __shfl_xor(s, 1); sq += __shfl_xor(sq, 1);
        s += __shfl_xor(s, 2); sq += __shfl_xor(sq, 2);
        s += __shfl_xor(s, 4); sq += __shfl_xor(sq, 4);
        float mu  = s * (1.0f / 256.0f);
        float var = sq * (1.0f / 256.0f) - mu * mu;
        float inv = 1.0f / sqrtf(var + 1e-5f);
        char* dstx = (char*)xs[buf];
        char* dstr = (char*)rsdl;
        #pragma unroll
        for (int j = 0; j < 8; ++j) {
            int cf = sub + 8 * j;
            int off = r * 512 + (((cf >> 1) ^ (r & 7)) << 4) + (cf & 1) * 8;
            uint2 pr;
            pr.x = pk2(rv[j][0], rv[j][1]); pr.y = pk2(rv[j][2], rv[j][3]);
            *reinterpret_cast<uint2*>(dstr + off) = pr;
            f32x4 g = *reinterpret_cast<const f32x4*>(&lng[cf * 4]);
            f32x4 b = *reinterpret_cast<const f32x4*>(&lnb[cf * 4]);
            uint2 px;
            px.x = pk2((rv[j][0] - mu) * inv * g[0] + b[0], (rv[j][1] - mu) * inv * g[1] + b[1]);
            px.y = pk2((rv[j][2] - mu) * inv * g[2] + b[2], (rv[j][3] - mu) * inv * g[3] + b[3]);
            *reinterpret_cast<uint2*>(dstx + off) = px;
        }
    };

    load_res(0);
    __syncthreads();
    stage(0);
    load_res(1);
    __syncthreads();

    for (int t = 0; t < 4; ++t) {
        const int b = t & 1;
        const char* xbase = (const char*)xs[b];

        f32x4 acc[4][2];
        #pragma unroll
        for (int ct = 0; ct < 4; ++ct) { acc[ct][0] = (f32x4)0.f; acc[ct][1] = (f32x4)0.f; }
        #pragma unroll
        for (int kk = 0; kk < 8; ++kk) {
            int csw = ((kk * 4 + g4) ^ (r16 & 7)) << 4;
            bfrag b0 = *reinterpret_cast<const bfrag*>(xbase + r16 * 512 + csw);
            bfrag b1 = *reinterpret_cast<const bfrag*>(xbase + (16 + r16) * 512 + csw);
            #pragma unroll
            for (int ct = 0; ct < 4; ++ct) {
                bfrag wf = *reinterpret_cast<const bfrag*>(wbase + (size_t)ct * 16 * CH + kk * 32);
                acc[ct][0] = __builtin_amdgcn_mfma_f32_16x16x32_bf16(wf, b0, acc[ct][0], 0, 0, 0);
                acc[ct][1] = __builtin_amdgcn_mfma_f32_16x16x32_bf16(wf, b1, acc[ct][1], 0, 0, 0);
            }
        }

        // epilogue BEFORE restaging rsdl (barrier between protects rsdl)
        #pragma unroll
        for (int ct = 0; ct < 4; ++ct)
            #pragma unroll
            for (int rt = 0; rt < 2; ++rt) {
                int tokL = rt * 16 + r16;
                int cf   = wid * 16 + ct * 4 + g4;
                int off  = tokL * 512 + (((cf >> 1) ^ (tokL & 7)) << 4) + (cf & 1) * 8;
                ushort4 rb = *reinterpret_cast<const ushort4*>((const char*)rsdl + off);
                f32x4 vv;
                {
                    float v0 = acc[ct][rt][0] + bias4[ct][0];
                    float v1 = acc[ct][rt][1] + bias4[ct][1];
                    float v2 = acc[ct][rt][2] + bias4[ct][2];
                    float v3 = acc[ct][rt][3] + bias4[ct][3];
                    vv[0] = 0.5f * v0 * (1.0f + erff(v0 * 0.70710678118654752f)) + bf2f(rb.x);
                    vv[1] = 0.5f * v1 * (1.0f + erff(v1 * 0.70710678118654752f)) + bf2f(rb.y);
                    vv[2] = 0.5f * v2 * (1.0f + erff(v2 * 0.70710678118654752f)) + bf2f(rb.z);
                    vv[3] = 0.5f * v3 * (1.0f + erff(v3 * 0.70710678118654752f)) + bf2f(rb.w);
                }
                *reinterpret_cast<f32x4*>(out + (size_t)(tok0 + t * 32 + tokL) * CH + chb + ct * 16) = vv;
            }
        __syncthreads();                              // epilogue done -> rsdl free

        if (t < 3) stage(b ^ 1);
        if (t < 2) load_res(t + 2);
        __syncthreads();                              // xs[b^1]/rsdl staged
    }
}

extern "C" void kernel_launch(void* const* d_in, const int* in_sizes, int n_in,
                              void* d_out, int out_size, void* d_ws, size_t ws_size,
                              hipStream_t stream)
{
    const float* x     = (const float*)d_in[0];
    const float* ln_g  = (const float*)d_in[1];
    const float* ln_b  = (const float*)d_in[2];
    const float* wq_w  = (const float*)d_in[3];
    const float* wq_b  = (const float*)d_in[4];
    const float* wk_w  = (const float*)d_in[5];
    const float* wk_b  = (const float*)d_in[6];
    const float* wv_w  = (const float*)d_in[7];
    const float* wv_b  = (const float*)d_in[8];
    const float* mlp_w = (const float*)d_in[9];
    const float* mlp_b = (const float*)d_in[10];

    char* ws = (char*)d_ws;
    u16* wcat = (u16*)ws;                       // 768*256 bf16
    u16* wmb  = (u16*)(ws + 393216);            // 256*256 bf16
    u16* qbuf = (u16*)(ws + 524288);            // q, later attn output
    u16* kbuf = (u16*)d_out;                    // k,v live in d_out until K3 rewrites it
    u16* vbuf = (u16*)d_out + (size_t)NTOK * CH;

    swa_prep <<<256,  256, 0, stream>>>(wq_w, wk_w, wv_w, mlp_w, wcat, wmb);
    swa_qkv3 <<<1176, 256, 0, stream>>>(x, ln_g, ln_b, wcat, wq_b, wk_b, wv_b, qbuf, kbuf, vbuf);
    swa_attn <<<3584, 256, 0, stream>>>(qbuf, kbuf, vbuf, qbuf);
    swa_mlp3 <<<784,  256, 0, stream>>>(x, qbuf, ln_g, ln_b, wmb, mlp_b, (float*)d_out);
}

// Round 5
// 391.571 us; speedup vs baseline: 1.4032x; 1.4032x over previous
//
#include <hip/hip_runtime.h>

#define NTOK 100352   // 8*112*112
#define NPB  12544    // tokens per batch (112*112)
#define CH   256

typedef unsigned short u16;
typedef float f32x4 __attribute__((ext_vector_type(4)));
typedef short bfrag __attribute__((ext_vector_type(8)));   // 8 bf16 = 4 VGPRs

static __device__ __forceinline__ u16 f2bf(float f) {
    union { float f; unsigned u; } v; v.f = f;
    unsigned r = v.u + 0x7FFFu + ((v.u >> 16) & 1u);   // RNE
    return (u16)(r >> 16);
}
static __device__ __forceinline__ float bf2f(u16 h) {
    union { unsigned u; float f; } v; v.u = ((unsigned)h) << 16;
    return v.f;
}
static __device__ __forceinline__ unsigned pk2(float a, float b) {
    return (unsigned)f2bf(a) | ((unsigned)f2bf(b) << 16);
}

// ---------------- K0: weight prep (fp32 -> bf16, fold q scale) ----------------
__global__ __launch_bounds__(256)
void swa_prep(const float* __restrict__ wq, const float* __restrict__ wk,
              const float* __restrict__ wv, const float* __restrict__ wm,
              u16* __restrict__ wcat, u16* __restrict__ wmb)
{
    int i0 = blockIdx.x * 256 + threadIdx.x;
    int stride = gridDim.x * 256;
    for (int i = i0; i < 768 * 256; i += stride) {
        int r = i >> 8, c = i & 255;
        float v;
        if (r < 256)      v = wq[r * 256 + c] * 0.0625f;      // fold d^-0.5 = 1/16
        else if (r < 512) v = wk[(r - 256) * 256 + c];
        else              v = wv[(r - 512) * 256 + c];
        wcat[i] = f2bf(v);
    }
    for (int i = i0; i < 256 * 256; i += stride) wmb[i] = f2bf(wm[i]);
}

// ---------------- K1a: roll + LN -> xn (bf16), one wave per token ----------------
__global__ __launch_bounds__(256)
void swa_ln(const float* __restrict__ x,
            const float* __restrict__ ln_g, const float* __restrict__ ln_b,
            u16* __restrict__ xn)
{
    const int lane = threadIdx.x & 63;
    const int wid  = threadIdx.x >> 6;
    f32x4 lg = *reinterpret_cast<const f32x4*>(ln_g + lane * 4);
    f32x4 lb = *reinterpret_cast<const f32x4*>(ln_b + lane * 4);

    const int wtok0 = (blockIdx.x * 4 + wid) * 16;    // 16 consecutive tokens per wave
    for (int i = 0; i < 16; ++i) {
        int tok = wtok0 + i;
        int b_  = tok / NPB;
        int rem = tok - b_ * NPB;
        int h = rem / 112, w = rem - h * 112;
        int h0 = h - 3 + ((h < 3) ? 112 : 0);         // shifted read
        int w0 = w - 3 + ((w < 3) ? 112 : 0);
        f32x4 v = *reinterpret_cast<const f32x4*>(x + (size_t)(b_ * NPB + h0 * 112 + w0) * CH + lane * 4);
        float s  = v[0] + v[1] + v[2] + v[3];
        float sq = v[0]*v[0] + v[1]*v[1] + v[2]*v[2] + v[3]*v[3];
        #pragma unroll
        for (int m = 1; m < 64; m <<= 1) { s += __shfl_xor(s, m); sq += __shfl_xor(sq, m); }
        float mu  = s * (1.0f / 256.0f);
        float var = sq * (1.0f / 256.0f) - mu * mu;
        float inv = 1.0f / sqrtf(var + 1e-5f);
        uint2 p;
        p.x = pk2((v[0] - mu) * inv * lg[0] + lb[0], (v[1] - mu) * inv * lg[1] + lb[1]);
        p.y = pk2((v[2] - mu) * inv * lg[2] + lb[2], (v[3] - mu) * inv * lg[3] + lb[3]);
        *reinterpret_cast<uint2*>(xn + (size_t)tok * CH + lane * 4) = p;
    }
}

// ---------------- K1b: GEMM xn @ Wqkv^T (+bias, k-norm); q in-place over xn ----------------
// grid 1568 blocks x 64 tokens; 512 thr / 8 waves = 2 token-halves x 4 ch-quarters.
// No A-LDS: xn B-frags from global (L1), weights from L2. One barrier (k-norm + WAR on xn).
__global__ __launch_bounds__(512)
void swa_qkv4(const u16* __restrict__ xn, const u16* __restrict__ wcat,
              const float* __restrict__ bq, const float* __restrict__ bk,
              const float* __restrict__ bv,
              u16* __restrict__ qbuf, u16* __restrict__ kbuf, u16* __restrict__ vbuf)
{
    __shared__ float knL[2][32][4];
    __shared__ float biasL[768];

    const int tid  = threadIdx.x;
    const int lane = tid & 63;
    const int w    = tid >> 6;
    const int r16  = lane & 15;
    const int g4   = lane >> 4;
    const int th   = w & 1;                           // token half
    const int chq  = w >> 1;                          // channel quarter

    const int swz  = (blockIdx.x & 7) * 196 + (blockIdx.x >> 3);   // 1568 = 8*196
    const int tok0 = swz * 64;
    const int tokB = tok0 + th * 32;

    for (int j = tid; j < 768; j += 512)              // FIX: cover all 768 with 512 thr
        biasL[j] = (j < 256) ? bq[j] * 0.0625f : (j < 512 ? bk[j - 256] : bv[j - 512]);
    __syncthreads();                                  // FIX: biasL visible to all waves

    f32x4 acc[12][2];
    #pragma unroll
    for (int ct = 0; ct < 12; ++ct) { acc[ct][0] = (f32x4)0.f; acc[ct][1] = (f32x4)0.f; }

    const u16* xb0 = xn + (size_t)(tokB + r16) * CH + g4 * 8;
    const u16* xb1 = xn + (size_t)(tokB + 16 + r16) * CH + g4 * 8;
    const u16* wb  = wcat + (size_t)(chq * 64 + r16) * CH + g4 * 8;   // + (s*256 + c4*16)*CH

    #pragma unroll
    for (int kk = 0; kk < 8; ++kk) {
        bfrag b0 = *reinterpret_cast<const bfrag*>(xb0 + kk * 32);
        bfrag b1 = *reinterpret_cast<const bfrag*>(xb1 + kk * 32);
        #pragma unroll
        for (int ct = 0; ct < 12; ++ct) {
            int s = ct >> 2, c4 = ct & 3;
            bfrag a = *reinterpret_cast<const bfrag*>(wb + (size_t)(s * 256 + c4 * 16) * CH + kk * 32);
            acc[ct][0] = __builtin_amdgcn_mfma_f32_16x16x32_bf16(a, b0, acc[ct][0], 0, 0, 0);
            acc[ct][1] = __builtin_amdgcn_mfma_f32_16x16x32_bf16(a, b1, acc[ct][1], 0, 0, 0);
        }
    }

    // bias (LDS) + k-norm partials
    #pragma unroll
    for (int ct = 0; ct < 12; ++ct) {
        int s = ct >> 2, c4 = ct & 3;
        f32x4 bb = *reinterpret_cast<const f32x4*>(&biasL[s * 256 + chq * 64 + c4 * 16 + g4 * 4]);
        #pragma unroll
        for (int rt = 0; rt < 2; ++rt)
            #pragma unroll
            for (int rr = 0; rr < 4; ++rr) acc[ct][rt][rr] += bb[rr];
    }
    float p0 = 0.f, p1 = 0.f;
    #pragma unroll
    for (int ct = 4; ct < 8; ++ct)
        #pragma unroll
        for (int rr = 0; rr < 4; ++rr) {
            p0 += acc[ct][0][rr] * acc[ct][0][rr];
            p1 += acc[ct][1][rr] * acc[ct][1][rr];
        }
    p0 += __shfl_xor(p0, 16); p0 += __shfl_xor(p0, 32);
    p1 += __shfl_xor(p1, 16); p1 += __shfl_xor(p1, 32);
    if (g4 == 0) { knL[th][r16][chq] = p0; knL[th][16 + r16][chq] = p1; }

    __syncthreads();   // knorm ready; all xn reads done (q may overwrite xn)

    float invn[2];
    #pragma unroll
    for (int rt = 0; rt < 2; ++rt) {
        f32x4 k4 = *reinterpret_cast<const f32x4*>(knL[th][rt * 16 + r16]);
        invn[rt] = 1.0f / fmaxf(sqrtf(k4[0] + k4[1] + k4[2] + k4[3]), 1e-12f);
    }

    #pragma unroll
    for (int rt = 0; rt < 2; ++rt) {
        int tok = tokB + rt * 16 + r16;
        #pragma unroll
        for (int ct = 0; ct < 12; ++ct) {
            int s = ct >> 2, c4 = ct & 3;
            float f = (s == 1) ? invn[rt] : 1.0f;
            u16* dst = (s == 0) ? qbuf : (s == 1) ? kbuf : vbuf;
            uint2 p;
            p.x = pk2(acc[ct][rt][0] * f, acc[ct][rt][1] * f);
            p.y = pk2(acc[ct][rt][2] * f, acc[ct][rt][3] * f);
            *reinterpret_cast<uint2*>(dst + (size_t)tok * CH + chq * 64 + c4 * 16 + g4 * 4) = p;
        }
    }
}

// ---------------- K2: local attention, one wave per 7-token window ----------------
__global__ __launch_bounds__(256)
void swa_attn(const u16* qbuf, const u16* kbuf, const u16* vbuf, u16* obuf)
{
    __shared__ float plds[4][16][17];
    const int tid  = threadIdx.x;
    const int lane = tid & 63;
    const int wid  = tid >> 6;
    const int win  = blockIdx.x * 4 + wid;
    const int iw   = win % 1792;
    const int base = win * 7;
    const int r16  = lane & 15;
    const int g4   = lane >> 4;

    int qrow = base + r16; if (qrow > NTOK - 1) qrow = NTOK - 1;
    int krow = base - 7 + r16; if (krow < 0) krow = 0;
    const u16* qp = qbuf + (size_t)qrow * CH + g4 * 8;
    const u16* kp = kbuf + (size_t)krow * CH + g4 * 8;

    f32x4 s4 = {0.f, 0.f, 0.f, 0.f};
    #pragma unroll
    for (int kk = 0; kk < 8; ++kk) {
        bfrag a = *reinterpret_cast<const bfrag*>(qp + kk * 32);
        bfrag b = *reinterpret_cast<const bfrag*>(kp + kk * 32);
        s4 = __builtin_amdgcn_mfma_f32_16x16x32_bf16(a, b, s4, 0, 0, 0);
    }

    const int  j     = r16;
    const bool first = (iw == 0);
    #pragma unroll
    for (int rr = 0; rr < 4; ++rr) {
        int i = g4 * 4 + rr;
        float s = s4[rr];
        if (j == i + 7) s = -5.0e4f;
        if (j > i + 7 || j >= 14 || (first && j < 7)) s = -3.0e38f;
        s4[rr] = s;
    }
    f32x4 mx = s4;
    #pragma unroll
    for (int off = 8; off; off >>= 1) {
        #pragma unroll
        for (int rr = 0; rr < 4; ++rr) mx[rr] = fmaxf(mx[rr], __shfl_xor(mx[rr], off));
    }
    f32x4 p;
    #pragma unroll
    for (int rr = 0; rr < 4; ++rr) p[rr] = __expf(s4[rr] - mx[rr]);
    f32x4 sm = p;
    #pragma unroll
    for (int off = 8; off; off >>= 1) {
        #pragma unroll
        for (int rr = 0; rr < 4; ++rr) sm[rr] += __shfl_xor(sm[rr], off);
    }
    #pragma unroll
    for (int rr = 0; rr < 4; ++rr) plds[wid][g4 * 4 + rr][j] = p[rr] / sm[rr];
    __syncthreads();

    f32x4 zero4 = {0.f, 0.f, 0.f, 0.f};
    f32x4 oa[7];
    #pragma unroll
    for (int i = 0; i < 7; ++i) oa[i] = zero4;
    for (int jj = 0; jj < 14; ++jj) {
        int vrow = base - 7 + jj;
        if (vrow < 0) vrow = 0;
        ushort4 vr = *reinterpret_cast<const ushort4*>(vbuf + (size_t)vrow * CH + lane * 4);
        f32x4 vvv; vvv[0] = bf2f(vr.x); vvv[1] = bf2f(vr.y); vvv[2] = bf2f(vr.z); vvv[3] = bf2f(vr.w);
        #pragma unroll
        for (int i = 0; i < 7; ++i) {
            float pp = plds[wid][i][jj];
            oa[i][0] += pp * vvv[0]; oa[i][1] += pp * vvv[1];
            oa[i][2] += pp * vvv[2]; oa[i][3] += pp * vvv[3];
        }
    }
    #pragma unroll
    for (int i = 0; i < 7; ++i) {
        ushort4 o; o.x = f2bf(oa[i][0]); o.y = f2bf(oa[i][1]); o.z = f2bf(oa[i][2]); o.w = f2bf(oa[i][3]);
        *reinterpret_cast<ushort4*>(obuf + (size_t)(base + i) * CH + lane * 4) = o;
    }
}

// ---------------- K3: unshift + residual + LN + MLP(GELU) + add ----------------
// R2 skeleton; MFMA operands swapped (A=W) -> lane holds 4 consecutive ch -> f32x4 stores.
__global__ __launch_bounds__(256)
void swa_mlp4(const float* __restrict__ x, const u16* __restrict__ abuf,
              const float* __restrict__ ln_g, const float* __restrict__ ln_b,
              const u16* __restrict__ wmb, const float* __restrict__ mbias,
              float* __restrict__ out)
{
    __shared__ u16   xs[32][264];
    __shared__ float rsd[32][260];
    __shared__ float bias[256];
    const int tid  = threadIdx.x;
    const int lane = tid & 63;
    const int wid  = tid >> 6;
    const int tok0 = blockIdx.x * 32;
    const int r16  = lane & 15;
    const int g4   = lane >> 4;

    if (tid < 256) bias[tid] = mbias[tid];
    f32x4 lg = *reinterpret_cast<const f32x4*>(ln_g + lane * 4);
    f32x4 lb = *reinterpret_cast<const f32x4*>(ln_b + lane * 4);

    for (int it = 0; it < 8; ++it) {
        int tt  = wid * 8 + it;
        int tok = tok0 + tt;
        int b_  = tok / NPB, rem = tok - b_ * NPB;
        int h = rem / 112, w = rem - h * 112;
        int hs = h + 3;  if (hs >= 112) hs -= 112;    // unshift
        int ws_ = w + 3; if (ws_ >= 112) ws_ -= 112;
        const u16* arow = abuf + (size_t)(b_ * NPB + hs * 112 + ws_) * CH;
        ushort4 av = *reinterpret_cast<const ushort4*>(arow + lane * 4);
        f32x4 xv = *reinterpret_cast<const f32x4*>(x + (size_t)tok * CH + lane * 4);
        f32x4 rv;
        rv[0] = xv[0] + bf2f(av.x); rv[1] = xv[1] + bf2f(av.y);
        rv[2] = xv[2] + bf2f(av.z); rv[3] = xv[3] + bf2f(av.w);
        *reinterpret_cast<f32x4*>(&rsd[tt][lane * 4]) = rv;
        float s  = rv[0] + rv[1] + rv[2] + rv[3];
        float sq = rv[0]*rv[0] + rv[1]*rv[1] + rv[2]*rv[2] + rv[3]*rv[3];
        #pragma unroll
        for (int m = 32; m; m >>= 1) { s += __shfl_xor(s, m); sq += __shfl_xor(sq, m); }
        float mu  = s * (1.0f / 256.0f);
        float var = sq * (1.0f / 256.0f) - mu * mu;
        float inv = 1.0f / sqrtf(var + 1e-5f);
        ushort4 o;
        o.x = f2bf((rv[0] - mu) * inv * lg[0] + lb[0]);
        o.y = f2bf((rv[1] - mu) * inv * lg[1] + lb[1]);
        o.z = f2bf((rv[2] - mu) * inv * lg[2] + lb[2]);
        o.w = f2bf((rv[3] - mu) * inv * lg[3] + lb[3]);
        *reinterpret_cast<ushort4*>(&xs[tt][lane * 4]) = o;
    }
    __syncthreads();

    f32x4 acc[4][2];
    #pragma unroll
    for (int i = 0; i < 4; ++i) { acc[i][0] = (f32x4)0.f; acc[i][1] = (f32x4)0.f; }

    #pragma unroll
    for (int kk = 0; kk < 8; ++kk) {
        bfrag b0 = *reinterpret_cast<const bfrag*>(&xs[r16][kk * 32 + g4 * 8]);
        bfrag b1 = *reinterpret_cast<const bfrag*>(&xs[16 + r16][kk * 32 + g4 * 8]);
        #pragma unroll
        for (int ct = 0; ct < 4; ++ct) {
            // A = weights: row = out-channel (wid*64 + ct*16 + r16)
            bfrag wf = *reinterpret_cast<const bfrag*>(wmb + (size_t)(wid * 64 + ct * 16 + r16) * CH + kk * 32 + g4 * 8);
            acc[ct][0] = __builtin_amdgcn_mfma_f32_16x16x32_bf16(wf, b0, acc[ct][0], 0, 0, 0);
            acc[ct][1] = __builtin_amdgcn_mfma_f32_16x16x32_bf16(wf, b1, acc[ct][1], 0, 0, 0);
        }
    }

    // D: row = channel = ct*16 + g4*4+rr (+wid*64), col = token = rt*16 + r16
    #pragma unroll
    for (int ct = 0; ct < 4; ++ct) {
        int ch = wid * 64 + ct * 16 + g4 * 4;
        f32x4 bb = *reinterpret_cast<const f32x4*>(&bias[ch]);
        #pragma unroll
        for (int rt = 0; rt < 2; ++rt) {
            int tokL = rt * 16 + r16;
            f32x4 rb = *reinterpret_cast<const f32x4*>(&rsd[tokL][ch]);
            f32x4 vv;
            #pragma unroll
            for (int rr = 0; rr < 4; ++rr) {
                float val = acc[ct][rt][rr] + bb[rr];
                vv[rr] = 0.5f * val * (1.0f + erff(val * 0.70710678118654752f)) + rb[rr];
            }
            *reinterpret_cast<f32x4*>(out + (size_t)(tok0 + tokL) * CH + ch) = vv;
        }
    }
}

extern "C" void kernel_launch(void* const* d_in, const int* in_sizes, int n_in,
                              void* d_out, int out_size, void* d_ws, size_t ws_size,
                              hipStream_t stream)
{
    const float* x     = (const float*)d_in[0];
    const float* ln_g  = (const float*)d_in[1];
    const float* ln_b  = (const float*)d_in[2];
    const float* wq_w  = (const float*)d_in[3];
    const float* wq_b  = (const float*)d_in[4];
    const float* wk_w  = (const float*)d_in[5];
    const float* wk_b  = (const float*)d_in[6];
    const float* wv_w  = (const float*)d_in[7];
    const float* wv_b  = (const float*)d_in[8];
    const float* mlp_w = (const float*)d_in[9];
    const float* mlp_b = (const float*)d_in[10];

    char* ws = (char*)d_ws;
    u16* wcat = (u16*)ws;                       // 768*256 bf16
    u16* wmb  = (u16*)(ws + 393216);            // 256*256 bf16
    u16* xnq  = (u16*)(ws + 524288);            // xn; q overwrites in-place; then attn output
    u16* kbuf = (u16*)d_out;                    // k,v live in d_out until K3 rewrites it
    u16* vbuf = (u16*)d_out + (size_t)NTOK * CH;

    swa_prep <<<256,  256, 0, stream>>>(wq_w, wk_w, wv_w, mlp_w, wcat, wmb);
    swa_ln   <<<1568, 256, 0, stream>>>(x, ln_g, ln_b, xnq);
    swa_qkv4 <<<1568, 512, 0, stream>>>(xnq, wcat, wq_b, wk_b, wv_b, xnq, kbuf, vbuf);
    swa_attn <<<3584, 256, 0, stream>>>(xnq, kbuf, vbuf, xnq);
    swa_mlp4 <<<3136, 256, 0, stream>>>(x, xnq, ln_g, ln_b, wmb, mlp_b, (float*)d_out);
}

// Round 6
// 310.378 us; speedup vs baseline: 1.7702x; 1.2616x over previous
//
#include <hip/hip_runtime.h>

#define NTOK 100352   // 8*112*112
#define NPB  12544    // tokens per batch (112*112)
#define CH   256

typedef unsigned short u16;
typedef float f32x4 __attribute__((ext_vector_type(4)));
typedef short bfrag __attribute__((ext_vector_type(8)));   // 8 bf16 = 4 VGPRs

static __device__ __forceinline__ u16 f2bf(float f) {
    union { float f; unsigned u; } v; v.f = f;
    unsigned r = v.u + 0x7FFFu + ((v.u >> 16) & 1u);   // RNE
    return (u16)(r >> 16);
}
static __device__ __forceinline__ float bf2f(u16 h) {
    union { unsigned u; float f; } v; v.u = ((unsigned)h) << 16;
    return v.f;
}
static __device__ __forceinline__ unsigned pk2(float a, float b) {
    return (unsigned)f2bf(a) | ((unsigned)f2bf(b) << 16);
}

// ---------------- K0: weight prep (fp32 -> bf16, fold q scale) ----------------
__global__ __launch_bounds__(256)
void swa_prep(const float* __restrict__ wq, const float* __restrict__ wk,
              const float* __restrict__ wv, const float* __restrict__ wm,
              u16* __restrict__ wcat, u16* __restrict__ wmb)
{
    int i0 = blockIdx.x * 256 + threadIdx.x;
    int stride = gridDim.x * 256;
    for (int i = i0; i < 768 * 256; i += stride) {
        int r = i >> 8, c = i & 255;
        float v;
        if (r < 256)      v = wq[r * 256 + c] * 0.0625f;      // fold d^-0.5 = 1/16
        else if (r < 512) v = wk[(r - 256) * 256 + c];
        else              v = wv[(r - 512) * 256 + c];
        wcat[i] = f2bf(v);
    }
    for (int i = i0; i < 256 * 256; i += stride) wmb[i] = f2bf(wm[i]);
}

// ---------------- K1a: roll + LN -> xn (bf16), one wave per token ----------------
__global__ __launch_bounds__(256)
void swa_ln(const float* __restrict__ x,
            const float* __restrict__ ln_g, const float* __restrict__ ln_b,
            u16* __restrict__ xn)
{
    const int lane = threadIdx.x & 63;
    const int wid  = threadIdx.x >> 6;
    f32x4 lg = *reinterpret_cast<const f32x4*>(ln_g + lane * 4);
    f32x4 lb = *reinterpret_cast<const f32x4*>(ln_b + lane * 4);

    const int wtok0 = (blockIdx.x * 4 + wid) * 16;
    for (int i = 0; i < 16; ++i) {
        int tok = wtok0 + i;
        int b_  = tok / NPB;
        int rem = tok - b_ * NPB;
        int h = rem / 112, w = rem - h * 112;
        int h0 = h - 3 + ((h < 3) ? 112 : 0);         // shifted read
        int w0 = w - 3 + ((w < 3) ? 112 : 0);
        f32x4 v = *reinterpret_cast<const f32x4*>(x + (size_t)(b_ * NPB + h0 * 112 + w0) * CH + lane * 4);
        float s  = v[0] + v[1] + v[2] + v[3];
        float sq = v[0]*v[0] + v[1]*v[1] + v[2]*v[2] + v[3]*v[3];
        #pragma unroll
        for (int m = 1; m < 64; m <<= 1) { s += __shfl_xor(s, m); sq += __shfl_xor(sq, m); }
        float mu  = s * (1.0f / 256.0f);
        float var = sq * (1.0f / 256.0f) - mu * mu;
        float inv = 1.0f / sqrtf(var + 1e-5f);
        uint2 p;
        p.x = pk2((v[0] - mu) * inv * lg[0] + lb[0], (v[1] - mu) * inv * lg[1] + lb[1]);
        p.y = pk2((v[2] - mu) * inv * lg[2] + lb[2], (v[3] - mu) * inv * lg[3] + lb[3]);
        *reinterpret_cast<uint2*>(xn + (size_t)tok * CH + lane * 4) = p;
    }
}

// ---------------- K1b: GEMM xn @ Wqkv^T + bias (NO k-norm; q in-place over xn) ----
// block = 64 tokens x 768 ch. X-tile (full K) staged once in swizzled LDS (32 KB);
// W double-buffered 128x64 tiles (2x16 KB). 24 steps, 1 barrier/step.
// 4 waves: wch = ch-64-half of 128-panel, wtk = tok-32-half.
__global__ __launch_bounds__(256)
void swa_qkv5(const u16* __restrict__ xn, const u16* __restrict__ wcat,
              const float* __restrict__ bq, const float* __restrict__ bk,
              const float* __restrict__ bv,
              u16* __restrict__ qbuf, u16* __restrict__ kbuf, u16* __restrict__ vbuf)
{
    __shared__ u16 xt[64 * 256];        // 32 KB token tile, full K, XOR-swizzled
    __shared__ u16 wt[2][128 * 64];     // 2x16 KB weight K-tiles, XOR-swizzled

    const int tid  = threadIdx.x;
    const int lane = tid & 63;
    const int wid  = tid >> 6;
    const int r16  = lane & 15, g4 = lane >> 4;
    const int wch  = wid & 1;
    const int wtk  = wid >> 1;
    const int tkp  = (blockIdx.x & 7) * 196 + (blockIdx.x >> 3);   // 1568 = 8*196
    const int tok0 = tkp * 64;

    char* xb = (char*)xt;

    // ---- prologue: stage X tile (all xn reads for this block happen HERE) ----
    {
        uint4 v[8];
        #pragma unroll
        for (int it = 0; it < 8; ++it) {
            int cid = tid + it * 256;
            int row = cid >> 5, c = cid & 31;
            v[it] = *reinterpret_cast<const uint4*>(xn + (size_t)(tok0 + row) * CH + c * 8);
        }
        #pragma unroll
        for (int it = 0; it < 8; ++it) {
            int cid = tid + it * 256;
            int row = cid >> 5, c = cid & 31;
            *reinterpret_cast<uint4*>(xb + row * 512 + ((c ^ (row & 7)) << 4)) = v[it];
        }
    }

    uint4 wreg[4];
    auto wload = [&](int s) {
        int chp = s >> 2, t = s & 3;
        #pragma unroll
        for (int it = 0; it < 4; ++it) {
            int cid = tid + it * 256;
            int row = cid >> 3, c = cid & 7;
            wreg[it] = *reinterpret_cast<const uint4*>(wcat + (size_t)(chp * 128 + row) * CH + t * 64 + c * 8);
        }
    };
    auto wstore = [&](int p) {
        char* d = (char*)wt[p];
        #pragma unroll
        for (int it = 0; it < 4; ++it) {
            int cid = tid + it * 256;
            int row = cid >> 3, c = cid & 7;
            *reinterpret_cast<uint4*>(d + row * 128 + ((c ^ (row & 7)) << 4)) = wreg[it];
        }
    };
    wload(0); wstore(0);
    __syncthreads();

    f32x4 acc[4][2];
    #pragma unroll
    for (int fi = 0; fi < 4; ++fi) { acc[fi][0] = (f32x4)0.f; acc[fi][1] = (f32x4)0.f; }

    for (int s = 0; s < 24; ++s) {
        const int chp = s >> 2, t = s & 3, p = s & 1;
        if (s < 23) wload(s + 1);                      // issue next W loads early
        const char* wp = (const char*)wt[p];
        #pragma unroll
        for (int kk = 0; kk < 2; ++kk) {
            bfrag af[4], bfj[2];
            #pragma unroll
            for (int fi = 0; fi < 4; ++fi) {
                int row = wch * 64 + fi * 16 + r16;
                af[fi] = *reinterpret_cast<const bfrag*>(wp + row * 128 + ((((kk << 2) | g4) ^ (row & 7)) << 4));
            }
            #pragma unroll
            for (int fj = 0; fj < 2; ++fj) {
                int trow = wtk * 32 + fj * 16 + r16;
                int c = t * 8 + kk * 4 + g4;
                bfj[fj] = *reinterpret_cast<const bfrag*>(xb + trow * 512 + ((c ^ (trow & 7)) << 4));
            }
            #pragma unroll
            for (int fi = 0; fi < 4; ++fi)
                #pragma unroll
                for (int fj = 0; fj < 2; ++fj)
                    acc[fi][fj] = __builtin_amdgcn_mfma_f32_16x16x32_bf16(af[fi], bfj[fj], acc[fi][fj], 0, 0, 0);
        }
        if (t == 3) {                                   // panel done -> epilogue, reset acc
            int sec = chp >> 1;
            u16* outp = (sec == 0) ? qbuf : (sec == 1) ? kbuf : vbuf;
            const float* bp = (sec == 0) ? bq : (sec == 1) ? bk : bv;
            float bscale = (sec == 0) ? 0.0625f : 1.0f;
            int chl0 = (chp & 1) * 128 + wch * 64;
            #pragma unroll
            for (int fi = 0; fi < 4; ++fi) {
                int chl = chl0 + fi * 16 + g4 * 4;
                f32x4 bb = *reinterpret_cast<const f32x4*>(bp + chl);
                #pragma unroll
                for (int fj = 0; fj < 2; ++fj) {
                    int tok = tok0 + wtk * 32 + fj * 16 + r16;
                    uint2 pk;
                    pk.x = pk2(acc[fi][fj][0] + bb[0] * bscale, acc[fi][fj][1] + bb[1] * bscale);
                    pk.y = pk2(acc[fi][fj][2] + bb[2] * bscale, acc[fi][fj][3] + bb[3] * bscale);
                    *reinterpret_cast<uint2*>(outp + (size_t)tok * CH + chl) = pk;
                    acc[fi][fj] = (f32x4)0.f;
                }
            }
        }
        if (s < 23) wstore(p ^ 1);
        __syncthreads();
    }
}

// ---------------- K2: local attention + on-the-fly k-normalization ----------------
// score(i,j) = (q_i . k_j) / ||k_j|| ; k stored UNNORMALIZED bf16.
__global__ __launch_bounds__(256)
void swa_attn(const u16* qbuf, const u16* kbuf, const u16* vbuf, u16* obuf)
{
    __shared__ float plds[4][16][17];
    const int tid  = threadIdx.x;
    const int lane = tid & 63;
    const int wid  = tid >> 6;
    const int win  = blockIdx.x * 4 + wid;
    const int iw   = win % 1792;
    const int base = win * 7;
    const int r16  = lane & 15;
    const int g4   = lane >> 4;

    int qrow = base + r16; if (qrow > NTOK - 1) qrow = NTOK - 1;
    int krow = base - 7 + r16; if (krow < 0) krow = 0;
    const u16* qp = qbuf + (size_t)qrow * CH + g4 * 8;
    const u16* kp = kbuf + (size_t)krow * CH + g4 * 8;

    // load k fragments once; row sum-of-squares for the norm
    bfrag kf[8];
    #pragma unroll
    for (int kk = 0; kk < 8; ++kk) kf[kk] = *reinterpret_cast<const bfrag*>(kp + kk * 32);
    float sq = 0.f;
    #pragma unroll
    for (int kk = 0; kk < 8; ++kk)
        #pragma unroll
        for (int e = 0; e < 8; ++e) { float kv = bf2f((u16)kf[kk][e]); sq += kv * kv; }
    sq += __shfl_xor(sq, 16); sq += __shfl_xor(sq, 32);   // reduce over g4 (same key row)
    float invk = 1.0f / fmaxf(sqrtf(sq), 1e-12f);

    f32x4 s4 = {0.f, 0.f, 0.f, 0.f};
    #pragma unroll
    for (int kk = 0; kk < 8; ++kk) {
        bfrag a = *reinterpret_cast<const bfrag*>(qp + kk * 32);
        s4 = __builtin_amdgcn_mfma_f32_16x16x32_bf16(a, kf[kk], s4, 0, 0, 0);
    }

    const int  j     = r16;
    const bool first = (iw == 0);
    #pragma unroll
    for (int rr = 0; rr < 4; ++rr) {
        int i = g4 * 4 + rr;
        float s = s4[rr] * invk;                        // k-norm on the score column
        if (j == i + 7) s = -5.0e4f;
        if (j > i + 7 || j >= 14 || (first && j < 7)) s = -3.0e38f;
        s4[rr] = s;
    }
    f32x4 mx = s4;
    #pragma unroll
    for (int off = 8; off; off >>= 1) {
        #pragma unroll
        for (int rr = 0; rr < 4; ++rr) mx[rr] = fmaxf(mx[rr], __shfl_xor(mx[rr], off));
    }
    f32x4 p;
    #pragma unroll
    for (int rr = 0; rr < 4; ++rr) p[rr] = __expf(s4[rr] - mx[rr]);
    f32x4 sm = p;
    #pragma unroll
    for (int off = 8; off; off >>= 1) {
        #pragma unroll
        for (int rr = 0; rr < 4; ++rr) sm[rr] += __shfl_xor(sm[rr], off);
    }
    #pragma unroll
    for (int rr = 0; rr < 4; ++rr) plds[wid][g4 * 4 + rr][j] = p[rr] / sm[rr];
    __syncthreads();

    f32x4 zero4 = {0.f, 0.f, 0.f, 0.f};
    f32x4 oa[7];
    #pragma unroll
    for (int i = 0; i < 7; ++i) oa[i] = zero4;
    for (int jj = 0; jj < 14; ++jj) {
        int vrow = base - 7 + jj;
        if (vrow < 0) vrow = 0;
        ushort4 vr = *reinterpret_cast<const ushort4*>(vbuf + (size_t)vrow * CH + lane * 4);
        f32x4 vvv; vvv[0] = bf2f(vr.x); vvv[1] = bf2f(vr.y); vvv[2] = bf2f(vr.z); vvv[3] = bf2f(vr.w);
        #pragma unroll
        for (int i = 0; i < 7; ++i) {
            float pp = plds[wid][i][jj];
            oa[i][0] += pp * vvv[0]; oa[i][1] += pp * vvv[1];
            oa[i][2] += pp * vvv[2]; oa[i][3] += pp * vvv[3];
        }
    }
    #pragma unroll
    for (int i = 0; i < 7; ++i) {
        ushort4 o; o.x = f2bf(oa[i][0]); o.y = f2bf(oa[i][1]); o.z = f2bf(oa[i][2]); o.w = f2bf(oa[i][3]);
        *reinterpret_cast<ushort4*>(obuf + (size_t)(base + i) * CH + lane * 4) = o;
    }
}

// ---------------- K3: unshift + residual + LN + MLP(GELU) + add ----------------
__global__ __launch_bounds__(256)
void swa_mlp4(const float* __restrict__ x, const u16* __restrict__ abuf,
              const float* __restrict__ ln_g, const float* __restrict__ ln_b,
              const u16* __restrict__ wmb, const float* __restrict__ mbias,
              float* __restrict__ out)
{
    __shared__ u16   xs[32][264];
    __shared__ float rsd[32][260];
    __shared__ float bias[256];
    const int tid  = threadIdx.x;
    const int lane = tid & 63;
    const int wid  = tid >> 6;
    const int tok0 = blockIdx.x * 32;
    const int r16  = lane & 15;
    const int g4   = lane >> 4;

    if (tid < 256) bias[tid] = mbias[tid];
    f32x4 lg = *reinterpret_cast<const f32x4*>(ln_g + lane * 4);
    f32x4 lb = *reinterpret_cast<const f32x4*>(ln_b + lane * 4);

    for (int it = 0; it < 8; ++it) {
        int tt  = wid * 8 + it;
        int tok = tok0 + tt;
        int b_  = tok / NPB, rem = tok - b_ * NPB;
        int h = rem / 112, w = rem - h * 112;
        int hs = h + 3;  if (hs >= 112) hs -= 112;
        int ws_ = w + 3; if (ws_ >= 112) ws_ -= 112;
        const u16* arow = abuf + (size_t)(b_ * NPB + hs * 112 + ws_) * CH;
        ushort4 av = *reinterpret_cast<const ushort4*>(arow + lane * 4);
        f32x4 xv = *reinterpret_cast<const f32x4*>(x + (size_t)tok * CH + lane * 4);
        f32x4 rv;
        rv[0] = xv[0] + bf2f(av.x); rv[1] = xv[1] + bf2f(av.y);
        rv[2] = xv[2] + bf2f(av.z); rv[3] = xv[3] + bf2f(av.w);
        *reinterpret_cast<f32x4*>(&rsd[tt][lane * 4]) = rv;
        float s  = rv[0] + rv[1] + rv[2] + rv[3];
        float sq = rv[0]*rv[0] + rv[1]*rv[1] + rv[2]*rv[2] + rv[3]*rv[3];
        #pragma unroll
        for (int m = 32; m; m >>= 1) { s += __shfl_xor(s, m); sq += __shfl_xor(sq, m); }
        float mu  = s * (1.0f / 256.0f);
        float var = sq * (1.0f / 256.0f) - mu * mu;
        float inv = 1.0f / sqrtf(var + 1e-5f);
        ushort4 o;
        o.x = f2bf((rv[0] - mu) * inv * lg[0] + lb[0]);
        o.y = f2bf((rv[1] - mu) * inv * lg[1] + lb[1]);
        o.z = f2bf((rv[2] - mu) * inv * lg[2] + lb[2]);
        o.w = f2bf((rv[3] - mu) * inv * lg[3] + lb[3]);
        *reinterpret_cast<ushort4*>(&xs[tt][lane * 4]) = o;
    }
    __syncthreads();

    f32x4 acc[4][2];
    #pragma unroll
    for (int i = 0; i < 4; ++i) { acc[i][0] = (f32x4)0.f; acc[i][1] = (f32x4)0.f; }

    #pragma unroll
    for (int kk = 0; kk < 8; ++kk) {
        bfrag b0 = *reinterpret_cast<const bfrag*>(&xs[r16][kk * 32 + g4 * 8]);
        bfrag b1 = *reinterpret_cast<const bfrag*>(&xs[16 + r16][kk * 32 + g4 * 8]);
        #pragma unroll
        for (int ct = 0; ct < 4; ++ct) {
            bfrag wf = *reinterpret_cast<const bfrag*>(wmb + (size_t)(wid * 64 + ct * 16 + r16) * CH + kk * 32 + g4 * 8);
            acc[ct][0] = __builtin_amdgcn_mfma_f32_16x16x32_bf16(wf, b0, acc[ct][0], 0, 0, 0);
            acc[ct][1] = __builtin_amdgcn_mfma_f32_16x16x32_bf16(wf, b1, acc[ct][1], 0, 0, 0);
        }
    }

    #pragma unroll
    for (int ct = 0; ct < 4; ++ct) {
        int ch = wid * 64 + ct * 16 + g4 * 4;
        f32x4 bb = *reinterpret_cast<const f32x4*>(&bias[ch]);
        #pragma unroll
        for (int rt = 0; rt < 2; ++rt) {
            int tokL = rt * 16 + r16;
            f32x4 rb = *reinterpret_cast<const f32x4*>(&rsd[tokL][ch]);
            f32x4 vv;
            #pragma unroll
            for (int rr = 0; rr < 4; ++rr) {
                float val = acc[ct][rt][rr] + bb[rr];
                vv[rr] = 0.5f * val * (1.0f + erff(val * 0.70710678118654752f)) + rb[rr];
            }
            *reinterpret_cast<f32x4*>(out + (size_t)(tok0 + tokL) * CH + ch) = vv;
        }
    }
}

extern "C" void kernel_launch(void* const* d_in, const int* in_sizes, int n_in,
                              void* d_out, int out_size, void* d_ws, size_t ws_size,
                              hipStream_t stream)
{
    const float* x     = (const float*)d_in[0];
    const float* ln_g  = (const float*)d_in[1];
    const float* ln_b  = (const float*)d_in[2];
    const float* wq_w  = (const float*)d_in[3];
    const float* wq_b  = (const float*)d_in[4];
    const float* wk_w  = (const float*)d_in[5];
    const float* wk_b  = (const float*)d_in[6];
    const float* wv_w  = (const float*)d_in[7];
    const float* wv_b  = (const float*)d_in[8];
    const float* mlp_w = (const float*)d_in[9];
    const float* mlp_b = (const float*)d_in[10];

    char* ws = (char*)d_ws;
    u16* wcat = (u16*)ws;                       // 768*256 bf16
    u16* wmb  = (u16*)(ws + 393216);            // 256*256 bf16
    u16* xnq  = (u16*)(ws + 524288);            // xn -> q (in-place) -> attn output
    u16* kbuf = (u16*)d_out;                    // k,v live in d_out until K3 rewrites it
    u16* vbuf = (u16*)d_out + (size_t)NTOK * CH;

    swa_prep <<<256,  256, 0, stream>>>(wq_w, wk_w, wv_w, mlp_w, wcat, wmb);
    swa_ln   <<<1568, 256, 0, stream>>>(x, ln_g, ln_b, xnq);
    swa_qkv5 <<<1568, 256, 0, stream>>>(xnq, wcat, wq_b, wk_b, wv_b, xnq, kbuf, vbuf);
    swa_attn <<<3584, 256, 0, stream>>>(xnq, kbuf, vbuf, xnq);
    swa_mlp4 <<<3136, 256, 0, stream>>>(x, xnq, ln_g, ln_b, wmb, mlp_b, (float*)d_out);
}

// Round 7
// 305.214 us; speedup vs baseline: 1.8002x; 1.0169x over previous
//
#include <hip/hip_runtime.h>

#define NTOK 100352   // 8*112*112
#define NPB  12544    // tokens per batch (112*112)
#define CH   256

typedef unsigned short u16;
typedef float f32x4 __attribute__((ext_vector_type(4)));
typedef short bfrag __attribute__((ext_vector_type(8)));   // 8 bf16 = 4 VGPRs

static __device__ __forceinline__ u16 f2bf(float f) {
    union { float f; unsigned u; } v; v.f = f;
    unsigned r = v.u + 0x7FFFu + ((v.u >> 16) & 1u);   // RNE
    return (u16)(r >> 16);
}
static __device__ __forceinline__ float bf2f(u16 h) {
    union { unsigned u; float f; } v; v.u = ((unsigned)h) << 16;
    return v.f;
}
static __device__ __forceinline__ unsigned pk2(float a, float b) {
    return (unsigned)f2bf(a) | ((unsigned)f2bf(b) << 16);
}

// ---------------- K0: weight prep (fp32 -> bf16, fold q scale) ----------------
__global__ __launch_bounds__(256)
void swa_prep(const float* __restrict__ wq, const float* __restrict__ wk,
              const float* __restrict__ wv, const float* __restrict__ wm,
              u16* __restrict__ wcat, u16* __restrict__ wmb)
{
    int i0 = blockIdx.x * 256 + threadIdx.x;
    int stride = gridDim.x * 256;
    for (int i = i0; i < 768 * 256; i += stride) {
        int r = i >> 8, c = i & 255;
        float v;
        if (r < 256)      v = wq[r * 256 + c] * 0.0625f;      // fold d^-0.5 = 1/16
        else if (r < 512) v = wk[(r - 256) * 256 + c];
        else              v = wv[(r - 512) * 256 + c];
        wcat[i] = f2bf(v);
    }
    for (int i = i0; i < 256 * 256; i += stride) wmb[i] = f2bf(wm[i]);
}

// ---------------- K1a: roll + LN -> xn (bf16), one wave per token ----------------
__global__ __launch_bounds__(256)
void swa_ln(const float* __restrict__ x,
            const float* __restrict__ ln_g, const float* __restrict__ ln_b,
            u16* __restrict__ xn)
{
    const int lane = threadIdx.x & 63;
    const int wid  = threadIdx.x >> 6;
    f32x4 lg = *reinterpret_cast<const f32x4*>(ln_g + lane * 4);
    f32x4 lb = *reinterpret_cast<const f32x4*>(ln_b + lane * 4);

    const int wtok0 = (blockIdx.x * 4 + wid) * 16;
    for (int i = 0; i < 16; ++i) {
        int tok = wtok0 + i;
        int b_  = tok / NPB;
        int rem = tok - b_ * NPB;
        int h = rem / 112, w = rem - h * 112;
        int h0 = h - 3 + ((h < 3) ? 112 : 0);         // shifted read
        int w0 = w - 3 + ((w < 3) ? 112 : 0);
        f32x4 v = *reinterpret_cast<const f32x4*>(x + (size_t)(b_ * NPB + h0 * 112 + w0) * CH + lane * 4);
        float s  = v[0] + v[1] + v[2] + v[3];
        float sq = v[0]*v[0] + v[1]*v[1] + v[2]*v[2] + v[3]*v[3];
        #pragma unroll
        for (int m = 1; m < 64; m <<= 1) { s += __shfl_xor(s, m); sq += __shfl_xor(sq, m); }
        float mu  = s * (1.0f / 256.0f);
        float var = sq * (1.0f / 256.0f) - mu * mu;
        float inv = 1.0f / sqrtf(var + 1e-5f);
        uint2 p;
        p.x = pk2((v[0] - mu) * inv * lg[0] + lb[0], (v[1] - mu) * inv * lg[1] + lb[1]);
        p.y = pk2((v[2] - mu) * inv * lg[2] + lb[2], (v[3] - mu) * inv * lg[3] + lb[3]);
        *reinterpret_cast<uint2*>(xn + (size_t)tok * CH + lane * 4) = p;
    }
}

// ---------------- K1b: GEMM xn @ Wqkv^T + bias; X stationary in VGPRs ----------
// 784 blocks (=8*98) x 128 tokens; 4 waves token-split (32 tok/wave).
// X B-frags loaded ONCE into 64 VGPR; W streams via 2x8KB swizzled LDS panels
// [64ch][64K]; 48 steps = 12 panels x 4 K-steps; 1 barrier/step.
__global__ __launch_bounds__(256)
void swa_qkv6(const u16* __restrict__ xn, const u16* __restrict__ wcat,
              const float* __restrict__ bq, const float* __restrict__ bk,
              const float* __restrict__ bv,
              u16* __restrict__ qbuf, u16* __restrict__ kbuf, u16* __restrict__ vbuf)
{
    __shared__ u16 wt[2][64 * 64];                    // 2 x 8 KB, chunk-XOR swizzled

    const int tid  = threadIdx.x;
    const int lane = tid & 63;
    const int wid  = tid >> 6;
    const int r16  = lane & 15, g4 = lane >> 4;
    const int swz  = (blockIdx.x & 7) * 98 + (blockIdx.x >> 3);
    const int tok0 = swz * 128;
    const int trow0 = wid * 32;

    // ---- prologue: this wave's 32 tokens -> registers (only xn reads in block) ----
    bfrag bx[2][8];
    #pragma unroll
    for (int fj = 0; fj < 2; ++fj) {
        const u16* xp = xn + (size_t)(tok0 + trow0 + fj * 16 + r16) * CH + g4 * 8;
        #pragma unroll
        for (int kk = 0; kk < 8; ++kk)
            bx[fj][kk] = *reinterpret_cast<const bfrag*>(xp + kk * 32);
    }

    uint4 wreg[2];
    auto wload = [&](int s) {                          // s in [0,48)
        int pp = s >> 2, t = s & 3;
        #pragma unroll
        for (int it = 0; it < 2; ++it) {
            int cid = tid + it * 256;
            int row = cid >> 3, c = cid & 7;
            wreg[it] = *reinterpret_cast<const uint4*>(wcat + (size_t)(pp * 64 + row) * CH + t * 64 + c * 8);
        }
    };
    auto wstore = [&](int p) {
        char* d = (char*)wt[p];
        #pragma unroll
        for (int it = 0; it < 2; ++it) {
            int cid = tid + it * 256;
            int row = cid >> 3, c = cid & 7;
            *reinterpret_cast<uint4*>(d + row * 128 + ((c ^ (row & 7)) << 4)) = wreg[it];
        }
    };

    wload(0); wstore(0);
    __syncthreads();

    f32x4 acc[4][2];
    #pragma unroll
    for (int fi = 0; fi < 4; ++fi) { acc[fi][0] = (f32x4)0.f; acc[fi][1] = (f32x4)0.f; }

    for (int pp = 0; pp < 12; ++pp) {
        #pragma unroll
        for (int t = 0; t < 4; ++t) {
            const int s = pp * 4 + t;
            const int p = s & 1;
            if (s < 47) wload(s + 1);                  // issue next W tile loads early
            const char* wp = (const char*)wt[p];
            #pragma unroll
            for (int kk = 0; kk < 2; ++kk) {
                bfrag af[4];
                #pragma unroll
                for (int fi = 0; fi < 4; ++fi) {
                    int row = fi * 16 + r16;
                    af[fi] = *reinterpret_cast<const bfrag*>(wp + row * 128 + (((kk * 4 + g4) ^ (row & 7)) << 4));
                }
                #pragma unroll
                for (int fi = 0; fi < 4; ++fi)
                    #pragma unroll
                    for (int fj = 0; fj < 2; ++fj)
                        acc[fi][fj] = __builtin_amdgcn_mfma_f32_16x16x32_bf16(af[fi], bx[fj][t * 2 + kk], acc[fi][fj], 0, 0, 0);
            }
            if (t == 3) {                               // panel done -> epilogue
                const int sec = pp >> 2;                // 0=q 1=k 2=v
                u16* outp = (sec == 0) ? qbuf : (sec == 1) ? kbuf : vbuf;
                const float* bp = (sec == 0) ? bq : (sec == 1) ? bk : bv;
                const float bscale = (sec == 0) ? 0.0625f : 1.0f;
                #pragma unroll
                for (int fi = 0; fi < 4; ++fi) {
                    int chl = (pp & 3) * 64 + fi * 16 + g4 * 4;   // channel within section
                    f32x4 bb = *reinterpret_cast<const f32x4*>(bp + chl);
                    #pragma unroll
                    for (int fj = 0; fj < 2; ++fj) {
                        int tok = tok0 + trow0 + fj * 16 + r16;
                        uint2 pk;
                        pk.x = pk2(acc[fi][fj][0] + bb[0] * bscale, acc[fi][fj][1] + bb[1] * bscale);
                        pk.y = pk2(acc[fi][fj][2] + bb[2] * bscale, acc[fi][fj][3] + bb[3] * bscale);
                        *reinterpret_cast<uint2*>(outp + (size_t)tok * CH + chl) = pk;
                        acc[fi][fj] = (f32x4)0.f;
                    }
                }
            }
            if (s < 47) wstore(p ^ 1);
            __syncthreads();
        }
    }
}

// ---------------- K2: local attention + on-the-fly k-normalization ----------------
// score(i,j) = (q_i . k_j) / ||k_j|| ; k stored UNNORMALIZED bf16.
__global__ __launch_bounds__(256)
void swa_attn(const u16* qbuf, const u16* kbuf, const u16* vbuf, u16* obuf)
{
    __shared__ float plds[4][16][17];
    const int tid  = threadIdx.x;
    const int lane = tid & 63;
    const int wid  = tid >> 6;
    const int win  = blockIdx.x * 4 + wid;
    const int iw   = win % 1792;
    const int base = win * 7;
    const int r16  = lane & 15;
    const int g4   = lane >> 4;

    int qrow = base + r16; if (qrow > NTOK - 1) qrow = NTOK - 1;
    int krow = base - 7 + r16; if (krow < 0) krow = 0;
    const u16* qp = qbuf + (size_t)qrow * CH + g4 * 8;
    const u16* kp = kbuf + (size_t)krow * CH + g4 * 8;

    bfrag kf[8];
    #pragma unroll
    for (int kk = 0; kk < 8; ++kk) kf[kk] = *reinterpret_cast<const bfrag*>(kp + kk * 32);
    float sq = 0.f;
    #pragma unroll
    for (int kk = 0; kk < 8; ++kk)
        #pragma unroll
        for (int e = 0; e < 8; ++e) { float kv = bf2f((u16)kf[kk][e]); sq += kv * kv; }
    sq += __shfl_xor(sq, 16); sq += __shfl_xor(sq, 32);
    float invk = 1.0f / fmaxf(sqrtf(sq), 1e-12f);

    f32x4 s4 = {0.f, 0.f, 0.f, 0.f};
    #pragma unroll
    for (int kk = 0; kk < 8; ++kk) {
        bfrag a = *reinterpret_cast<const bfrag*>(qp + kk * 32);
        s4 = __builtin_amdgcn_mfma_f32_16x16x32_bf16(a, kf[kk], s4, 0, 0, 0);
    }

    const int  j     = r16;
    const bool first = (iw == 0);
    #pragma unroll
    for (int rr = 0; rr < 4; ++rr) {
        int i = g4 * 4 + rr;
        float s = s4[rr] * invk;
        if (j == i + 7) s = -5.0e4f;
        if (j > i + 7 || j >= 14 || (first && j < 7)) s = -3.0e38f;
        s4[rr] = s;
    }
    f32x4 mx = s4;
    #pragma unroll
    for (int off = 8; off; off >>= 1) {
        #pragma unroll
        for (int rr = 0; rr < 4; ++rr) mx[rr] = fmaxf(mx[rr], __shfl_xor(mx[rr], off));
    }
    f32x4 p;
    #pragma unroll
    for (int rr = 0; rr < 4; ++rr) p[rr] = __expf(s4[rr] - mx[rr]);
    f32x4 sm = p;
    #pragma unroll
    for (int off = 8; off; off >>= 1) {
        #pragma unroll
        for (int rr = 0; rr < 4; ++rr) sm[rr] += __shfl_xor(sm[rr], off);
    }
    #pragma unroll
    for (int rr = 0; rr < 4; ++rr) plds[wid][g4 * 4 + rr][j] = p[rr] / sm[rr];
    __syncthreads();

    f32x4 zero4 = {0.f, 0.f, 0.f, 0.f};
    f32x4 oa[7];
    #pragma unroll
    for (int i = 0; i < 7; ++i) oa[i] = zero4;
    for (int jj = 0; jj < 14; ++jj) {
        int vrow = base - 7 + jj;
        if (vrow < 0) vrow = 0;
        ushort4 vr = *reinterpret_cast<const ushort4*>(vbuf + (size_t)vrow * CH + lane * 4);
        f32x4 vvv; vvv[0] = bf2f(vr.x); vvv[1] = bf2f(vr.y); vvv[2] = bf2f(vr.z); vvv[3] = bf2f(vr.w);
        #pragma unroll
        for (int i = 0; i < 7; ++i) {
            float pp = plds[wid][i][jj];
            oa[i][0] += pp * vvv[0]; oa[i][1] += pp * vvv[1];
            oa[i][2] += pp * vvv[2]; oa[i][3] += pp * vvv[3];
        }
    }
    #pragma unroll
    for (int i = 0; i < 7; ++i) {
        ushort4 o; o.x = f2bf(oa[i][0]); o.y = f2bf(oa[i][1]); o.z = f2bf(oa[i][2]); o.w = f2bf(oa[i][3]);
        *reinterpret_cast<ushort4*>(obuf + (size_t)(base + i) * CH + lane * 4) = o;
    }
}

// ---------------- K3: unshift + residual + LN + MLP(GELU) + add ----------------
__global__ __launch_bounds__(256)
void swa_mlp4(const float* __restrict__ x, const u16* __restrict__ abuf,
              const float* __restrict__ ln_g, const float* __restrict__ ln_b,
              const u16* __restrict__ wmb, const float* __restrict__ mbias,
              float* __restrict__ out)
{
    __shared__ u16   xs[32][264];
    __shared__ float rsd[32][260];
    __shared__ float bias[256];
    const int tid  = threadIdx.x;
    const int lane = tid & 63;
    const int wid  = tid >> 6;
    const int tok0 = blockIdx.x * 32;
    const int r16  = lane & 15;
    const int g4   = lane >> 4;

    if (tid < 256) bias[tid] = mbias[tid];
    f32x4 lg = *reinterpret_cast<const f32x4*>(ln_g + lane * 4);
    f32x4 lb = *reinterpret_cast<const f32x4*>(ln_b + lane * 4);

    for (int it = 0; it < 8; ++it) {
        int tt  = wid * 8 + it;
        int tok = tok0 + tt;
        int b_  = tok / NPB, rem = tok - b_ * NPB;
        int h = rem / 112, w = rem - h * 112;
        int hs = h + 3;  if (hs >= 112) hs -= 112;
        int ws_ = w + 3; if (ws_ >= 112) ws_ -= 112;
        const u16* arow = abuf + (size_t)(b_ * NPB + hs * 112 + ws_) * CH;
        ushort4 av = *reinterpret_cast<const ushort4*>(arow + lane * 4);
        f32x4 xv = *reinterpret_cast<const f32x4*>(x + (size_t)tok * CH + lane * 4);
        f32x4 rv;
        rv[0] = xv[0] + bf2f(av.x); rv[1] = xv[1] + bf2f(av.y);
        rv[2] = xv[2] + bf2f(av.z); rv[3] = xv[3] + bf2f(av.w);
        *reinterpret_cast<f32x4*>(&rsd[tt][lane * 4]) = rv;
        float s  = rv[0] + rv[1] + rv[2] + rv[3];
        float sq = rv[0]*rv[0] + rv[1]*rv[1] + rv[2]*rv[2] + rv[3]*rv[3];
        #pragma unroll
        for (int m = 32; m; m >>= 1) { s += __shfl_xor(s, m); sq += __shfl_xor(sq, m); }
        float mu  = s * (1.0f / 256.0f);
        float var = sq * (1.0f / 256.0f) - mu * mu;
        float inv = 1.0f / sqrtf(var + 1e-5f);
        ushort4 o;
        o.x = f2bf((rv[0] - mu) * inv * lg[0] + lb[0]);
        o.y = f2bf((rv[1] - mu) * inv * lg[1] + lb[1]);
        o.z = f2bf((rv[2] - mu) * inv * lg[2] + lb[2]);
        o.w = f2bf((rv[3] - mu) * inv * lg[3] + lb[3]);
        *reinterpret_cast<ushort4*>(&xs[tt][lane * 4]) = o;
    }
    __syncthreads();

    f32x4 acc[4][2];
    #pragma unroll
    for (int i = 0; i < 4; ++i) { acc[i][0] = (f32x4)0.f; acc[i][1] = (f32x4)0.f; }

    #pragma unroll
    for (int kk = 0; kk < 8; ++kk) {
        bfrag b0 = *reinterpret_cast<const bfrag*>(&xs[r16][kk * 32 + g4 * 8]);
        bfrag b1 = *reinterpret_cast<const bfrag*>(&xs[16 + r16][kk * 32 + g4 * 8]);
        #pragma unroll
        for (int ct = 0; ct < 4; ++ct) {
            bfrag wf = *reinterpret_cast<const bfrag*>(wmb + (size_t)(wid * 64 + ct * 16 + r16) * CH + kk * 32 + g4 * 8);
            acc[ct][0] = __builtin_amdgcn_mfma_f32_16x16x32_bf16(wf, b0, acc[ct][0], 0, 0, 0);
            acc[ct][1] = __builtin_amdgcn_mfma_f32_16x16x32_bf16(wf, b1, acc[ct][1], 0, 0, 0);
        }
    }

    #pragma unroll
    for (int ct = 0; ct < 4; ++ct) {
        int ch = wid * 64 + ct * 16 + g4 * 4;
        f32x4 bb = *reinterpret_cast<const f32x4*>(&bias[ch]);
        #pragma unroll
        for (int rt = 0; rt < 2; ++rt) {
            int tokL = rt * 16 + r16;
            f32x4 rb = *reinterpret_cast<const f32x4*>(&rsd[tokL][ch]);
            f32x4 vv;
            #pragma unroll
            for (int rr = 0; rr < 4; ++rr) {
                float val = acc[ct][rt][rr] + bb[rr];
                vv[rr] = 0.5f * val * (1.0f + erff(val * 0.70710678118654752f)) + rb[rr];
            }
            *reinterpret_cast<f32x4*>(out + (size_t)(tok0 + tokL) * CH + ch) = vv;
        }
    }
}

extern "C" void kernel_launch(void* const* d_in, const int* in_sizes, int n_in,
                              void* d_out, int out_size, void* d_ws, size_t ws_size,
                              hipStream_t stream)
{
    const float* x     = (const float*)d_in[0];
    const float* ln_g  = (const float*)d_in[1];
    const float* ln_b  = (const float*)d_in[2];
    const float* wq_w  = (const float*)d_in[3];
    const float* wq_b  = (const float*)d_in[4];
    const float* wk_w  = (const float*)d_in[5];
    const float* wk_b  = (const float*)d_in[6];
    const float* wv_w  = (const float*)d_in[7];
    const float* wv_b  = (const float*)d_in[8];
    const float* mlp_w = (const float*)d_in[9];
    const float* mlp_b = (const float*)d_in[10];

    char* ws = (char*)d_ws;
    u16* wcat = (u16*)ws;                       // 768*256 bf16
    u16* wmb  = (u16*)(ws + 393216);            // 256*256 bf16
    u16* xnq  = (u16*)(ws + 524288);            // xn -> q (in-place) -> attn output
    u16* kbuf = (u16*)d_out;                    // k,v live in d_out until K3 rewrites it
    u16* vbuf = (u16*)d_out + (size_t)NTOK * CH;

    swa_prep <<<256,  256, 0, stream>>>(wq_w, wk_w, wv_w, mlp_w, wcat, wmb);
    swa_ln   <<<1568, 256, 0, stream>>>(x, ln_g, ln_b, xnq);
    swa_qkv6 <<<784,  256, 0, stream>>>(xnq, wcat, wq_b, wk_b, wv_b, xnq, kbuf, vbuf);
    swa_attn <<<3584, 256, 0, stream>>>(xnq, kbuf, vbuf, xnq);
    swa_mlp4 <<<3136, 256, 0, stream>>>(x, xnq, ln_g, ln_b, wmb, mlp_b, (float*)d_out);
}

// Round 8
// 282.428 us; speedup vs baseline: 1.9454x; 1.0807x over previous
//
#include <hip/hip_runtime.h>

#define NTOK 100352   // 8*112*112
#define NPB  12544    // tokens per batch (112*112)
#define CH   256

typedef unsigned short u16;
typedef float f32x4 __attribute__((ext_vector_type(4)));
typedef short bfrag __attribute__((ext_vector_type(8)));   // 8 bf16 = 4 VGPRs

static __device__ __forceinline__ u16 f2bf(float f) {
    union { float f; unsigned u; } v; v.f = f;
    unsigned r = v.u + 0x7FFFu + ((v.u >> 16) & 1u);   // RNE
    return (u16)(r >> 16);
}
static __device__ __forceinline__ float bf2f(u16 h) {
    union { unsigned u; float f; } v; v.u = ((unsigned)h) << 16;
    return v.f;
}
static __device__ __forceinline__ unsigned pk2(float a, float b) {
    return (unsigned)f2bf(a) | ((unsigned)f2bf(b) << 16);
}
// async global->LDS, 16B per lane; LDS dest = wave-uniform base + lane*16 (linear)
static __device__ __forceinline__ void gl16(const u16* g, u16* l) {
    __builtin_amdgcn_global_load_lds(
        (const __attribute__((address_space(1))) void*)g,
        (__attribute__((address_space(3))) void*)l, 16, 0, 0);
}

// ---------------- K0: weight prep (fp32 -> bf16, fold q scale) ----------------
__global__ __launch_bounds__(256)
void swa_prep(const float* __restrict__ wq, const float* __restrict__ wk,
              const float* __restrict__ wv, const float* __restrict__ wm,
              u16* __restrict__ wcat, u16* __restrict__ wmb)
{
    int i0 = blockIdx.x * 256 + threadIdx.x;
    int stride = gridDim.x * 256;
    for (int i = i0; i < 768 * 256; i += stride) {
        int r = i >> 8, c = i & 255;
        float v;
        if (r < 256)      v = wq[r * 256 + c] * 0.0625f;      // fold d^-0.5 = 1/16
        else if (r < 512) v = wk[(r - 256) * 256 + c];
        else              v = wv[(r - 512) * 256 + c];
        wcat[i] = f2bf(v);
    }
    for (int i = i0; i < 256 * 256; i += stride) wmb[i] = f2bf(wm[i]);
}

// ---------------- K1a: roll + LN -> xn (bf16), one wave per token ----------------
__global__ __launch_bounds__(256)
void swa_ln(const float* __restrict__ x,
            const float* __restrict__ ln_g, const float* __restrict__ ln_b,
            u16* __restrict__ xn)
{
    const int lane = threadIdx.x & 63;
    const int wid  = threadIdx.x >> 6;
    f32x4 lg = *reinterpret_cast<const f32x4*>(ln_g + lane * 4);
    f32x4 lb = *reinterpret_cast<const f32x4*>(ln_b + lane * 4);

    const int wtok0 = (blockIdx.x * 4 + wid) * 16;
    for (int i = 0; i < 16; ++i) {
        int tok = wtok0 + i;
        int b_  = tok / NPB;
        int rem = tok - b_ * NPB;
        int h = rem / 112, w = rem - h * 112;
        int h0 = h - 3 + ((h < 3) ? 112 : 0);         // shifted read
        int w0 = w - 3 + ((w < 3) ? 112 : 0);
        f32x4 v = *reinterpret_cast<const f32x4*>(x + (size_t)(b_ * NPB + h0 * 112 + w0) * CH + lane * 4);
        float s  = v[0] + v[1] + v[2] + v[3];
        float sq = v[0]*v[0] + v[1]*v[1] + v[2]*v[2] + v[3]*v[3];
        #pragma unroll
        for (int m = 1; m < 64; m <<= 1) { s += __shfl_xor(s, m); sq += __shfl_xor(sq, m); }
        float mu  = s * (1.0f / 256.0f);
        float var = sq * (1.0f / 256.0f) - mu * mu;
        float inv = 1.0f / sqrtf(var + 1e-5f);
        uint2 p;
        p.x = pk2((v[0] - mu) * inv * lg[0] + lb[0], (v[1] - mu) * inv * lg[1] + lb[1]);
        p.y = pk2((v[2] - mu) * inv * lg[2] + lb[2], (v[3] - mu) * inv * lg[3] + lb[3]);
        *reinterpret_cast<uint2*>(xn + (size_t)tok * CH + lane * 4) = p;
    }
}

// ---------------- K1b: GEMM xn @ Wqkv^T + bias; X in VGPRs, W via global_load_lds ----
// 784 blocks (=8*98) x 128 tokens; 512 thr / 8 waves = 4 tok-groups(32) x 2 ch-groups(32).
// W panels [64ch][128K] = 16 KB double-buffered, staged by global_load_lds with
// PRE-SWIZZLED global source (LDS dest linear); 24 steps; buffer == kh.
#define QSTEP(KH, SPP, DOSTAGE)                                                        \
    {                                                                                  \
        if (DOSTAGE) {                                                                 \
            const int spp_ = (SPP);                                                    \
            _Pragma("unroll")                                                          \
            for (int it = 0; it < 2; ++it) {                                           \
                int o   = (tid + it * 512) * 16;                                       \
                int row = o >> 8;                                                      \
                int cp  = (o >> 4) & 15;                                               \
                int c   = (cp & 8) | ((cp & 7) ^ (row & 7));                           \
                const u16* gp = wcat + (size_t)(spp_ * 64 + row) * CH + ((KH) ^ 1) * 128 + c * 8; \
                gl16(gp, (u16*)wt[(KH) ^ 1] + o / 2);                                  \
            }                                                                          \
        }                                                                              \
        const char* wp = (const char*)wt[(KH)];                                        \
        _Pragma("unroll")                                                              \
        for (int kk = 0; kk < 4; ++kk) {                                               \
            bfrag af[2];                                                               \
            _Pragma("unroll")                                                          \
            for (int fi = 0; fi < 2; ++fi) {                                           \
                int row = wch * 32 + fi * 16 + r16;                                    \
                int cc  = kk * 4 + g4;                                                 \
                int cp  = (cc & 8) | ((cc & 7) ^ (r16 & 7));                           \
                af[fi]  = *reinterpret_cast<const bfrag*>(wp + row * 256 + cp * 16);   \
            }                                                                          \
            _Pragma("unroll")                                                          \
            for (int fi = 0; fi < 2; ++fi)                                             \
                _Pragma("unroll")                                                      \
                for (int fj = 0; fj < 2; ++fj)                                         \
                    acc[fi][fj] = __builtin_amdgcn_mfma_f32_16x16x32_bf16(af[fi], bx[fj][(KH) * 4 + kk], acc[fi][fj], 0, 0, 0); \
        }                                                                              \
    }

__global__ __launch_bounds__(512)
void swa_qkv7(const u16* __restrict__ xn, const u16* __restrict__ wcat,
              const float* __restrict__ bq, const float* __restrict__ bk,
              const float* __restrict__ bv,
              u16* __restrict__ qbuf, u16* __restrict__ kbuf, u16* __restrict__ vbuf)
{
    __shared__ u16 wt[2][64 * 128];                   // 2 x 16 KB, swizzle via source

    const int tid  = threadIdx.x;
    const int lane = tid & 63;
    const int wid  = tid >> 6;
    const int r16  = lane & 15, g4 = lane >> 4;
    const int wch  = wid & 1;                         // channel half of panel (32 ch)
    const int wtk  = wid >> 1;                        // token group (32 tok)
    const int swz  = (blockIdx.x & 7) * 98 + (blockIdx.x >> 3);   // 784 = 8*98 bijective
    const int tok0 = swz * 128;
    const int trow0 = wtk * 32;

    // prologue A: this wave's 32 tokens -> registers (the block's ONLY xn reads)
    bfrag bx[2][8];
    #pragma unroll
    for (int fj = 0; fj < 2; ++fj) {
        const u16* xp = xn + (size_t)(tok0 + trow0 + fj * 16 + r16) * CH + g4 * 8;
        #pragma unroll
        for (int kb = 0; kb < 8; ++kb)
            bx[fj][kb] = *reinterpret_cast<const bfrag*>(xp + kb * 32);
    }

    // prologue B: stage panel (pp=0, kh=0) into buffer 0
    #pragma unroll
    for (int it = 0; it < 2; ++it) {
        int o   = (tid + it * 512) * 16;
        int row = o >> 8;
        int cp  = (o >> 4) & 15;
        int c   = (cp & 8) | ((cp & 7) ^ (row & 7));
        gl16(wcat + (size_t)row * CH + c * 8, (u16*)wt[0] + o / 2);
    }
    __syncthreads();

    f32x4 acc[2][2];
    #pragma unroll
    for (int fi = 0; fi < 2; ++fi) { acc[fi][0] = (f32x4)0.f; acc[fi][1] = (f32x4)0.f; }

    for (int pp = 0; pp < 12; ++pp) {
        QSTEP(0, pp, true);                            // compute buf0 (kh=0), stage buf1 (kh=1)
        __syncthreads();
        QSTEP(1, pp + 1, pp < 11);                     // compute buf1 (kh=1), stage next buf0

        // epilogue: panel pp complete (full K) -> bias + pack + store
        {
            const int sec = pp >> 2;                   // 0=q 1=k 2=v
            u16* outp = (sec == 0) ? qbuf : (sec == 1) ? kbuf : vbuf;
            const float* bp = (sec == 0) ? bq : (sec == 1) ? bk : bv;
            const float bsc = (sec == 0) ? 0.0625f : 1.0f;
            #pragma unroll
            for (int fi = 0; fi < 2; ++fi) {
                int chl = (pp & 3) * 64 + wch * 32 + fi * 16 + g4 * 4;
                f32x4 bb = *reinterpret_cast<const f32x4*>(bp + chl);
                #pragma unroll
                for (int fj = 0; fj < 2; ++fj) {
                    int tok = tok0 + trow0 + fj * 16 + r16;
                    uint2 pk;
                    pk.x = pk2(acc[fi][fj][0] + bb[0] * bsc, acc[fi][fj][1] + bb[1] * bsc);
                    pk.y = pk2(acc[fi][fj][2] + bb[2] * bsc, acc[fi][fj][3] + bb[3] * bsc);
                    *reinterpret_cast<uint2*>(outp + (size_t)tok * CH + chl) = pk;
                    acc[fi][fj] = (f32x4)0.f;
                }
            }
        }
        __syncthreads();
    }
}

// ---------------- K2: local attention + on-the-fly k-normalization ----------------
__global__ __launch_bounds__(256)
void swa_attn(const u16* qbuf, const u16* kbuf, const u16* vbuf, u16* obuf)
{
    __shared__ float plds[4][16][17];
    const int tid  = threadIdx.x;
    const int lane = tid & 63;
    const int wid  = tid >> 6;
    const int win  = blockIdx.x * 4 + wid;
    const int iw   = win % 1792;
    const int base = win * 7;
    const int r16  = lane & 15;
    const int g4   = lane >> 4;

    int qrow = base + r16; if (qrow > NTOK - 1) qrow = NTOK - 1;
    int krow = base - 7 + r16; if (krow < 0) krow = 0;
    const u16* qp = qbuf + (size_t)qrow * CH + g4 * 8;
    const u16* kp = kbuf + (size_t)krow * CH + g4 * 8;

    bfrag kf[8];
    #pragma unroll
    for (int kk = 0; kk < 8; ++kk) kf[kk] = *reinterpret_cast<const bfrag*>(kp + kk * 32);
    float sq = 0.f;
    #pragma unroll
    for (int kk = 0; kk < 8; ++kk)
        #pragma unroll
        for (int e = 0; e < 8; ++e) { float kv = bf2f((u16)kf[kk][e]); sq += kv * kv; }
    sq += __shfl_xor(sq, 16); sq += __shfl_xor(sq, 32);
    float invk = 1.0f / fmaxf(sqrtf(sq), 1e-12f);

    f32x4 s4 = {0.f, 0.f, 0.f, 0.f};
    #pragma unroll
    for (int kk = 0; kk < 8; ++kk) {
        bfrag a = *reinterpret_cast<const bfrag*>(qp + kk * 32);
        s4 = __builtin_amdgcn_mfma_f32_16x16x32_bf16(a, kf[kk], s4, 0, 0, 0);
    }

    const int  j     = r16;
    const bool first = (iw == 0);
    #pragma unroll
    for (int rr = 0; rr < 4; ++rr) {
        int i = g4 * 4 + rr;
        float s = s4[rr] * invk;
        if (j == i + 7) s = -5.0e4f;
        if (j > i + 7 || j >= 14 || (first && j < 7)) s = -3.0e38f;
        s4[rr] = s;
    }
    f32x4 mx = s4;
    #pragma unroll
    for (int off = 8; off; off >>= 1) {
        #pragma unroll
        for (int rr = 0; rr < 4; ++rr) mx[rr] = fmaxf(mx[rr], __shfl_xor(mx[rr], off));
    }
    f32x4 p;
    #pragma unroll
    for (int rr = 0; rr < 4; ++rr) p[rr] = __expf(s4[rr] - mx[rr]);
    f32x4 sm = p;
    #pragma unroll
    for (int off = 8; off; off >>= 1) {
        #pragma unroll
        for (int rr = 0; rr < 4; ++rr) sm[rr] += __shfl_xor(sm[rr], off);
    }
    #pragma unroll
    for (int rr = 0; rr < 4; ++rr) plds[wid][g4 * 4 + rr][j] = p[rr] / sm[rr];
    __syncthreads();

    f32x4 zero4 = {0.f, 0.f, 0.f, 0.f};
    f32x4 oa[7];
    #pragma unroll
    for (int i = 0; i < 7; ++i) oa[i] = zero4;
    for (int jj = 0; jj < 14; ++jj) {
        int vrow = base - 7 + jj;
        if (vrow < 0) vrow = 0;
        ushort4 vr = *reinterpret_cast<const ushort4*>(vbuf + (size_t)vrow * CH + lane * 4);
        f32x4 vvv; vvv[0] = bf2f(vr.x); vvv[1] = bf2f(vr.y); vvv[2] = bf2f(vr.z); vvv[3] = bf2f(vr.w);
        #pragma unroll
        for (int i = 0; i < 7; ++i) {
            float pp = plds[wid][i][jj];
            oa[i][0] += pp * vvv[0]; oa[i][1] += pp * vvv[1];
            oa[i][2] += pp * vvv[2]; oa[i][3] += pp * vvv[3];
        }
    }
    #pragma unroll
    for (int i = 0; i < 7; ++i) {
        ushort4 o; o.x = f2bf(oa[i][0]); o.y = f2bf(oa[i][1]); o.z = f2bf(oa[i][2]); o.w = f2bf(oa[i][3]);
        *reinterpret_cast<ushort4*>(obuf + (size_t)(base + i) * CH + lane * 4) = o;
    }
}

// ---------------- K3: unshift + residual + LN + MLP(GELU) + add ----------------
__global__ __launch_bounds__(256)
void swa_mlp4(const float* __restrict__ x, const u16* __restrict__ abuf,
              const float* __restrict__ ln_g, const float* __restrict__ ln_b,
              const u16* __restrict__ wmb, const float* __restrict__ mbias,
              float* __restrict__ out)
{
    __shared__ u16   xs[32][264];
    __shared__ float rsd[32][260];
    __shared__ float bias[256];
    const int tid  = threadIdx.x;
    const int lane = tid & 63;
    const int wid  = tid >> 6;
    const int tok0 = blockIdx.x * 32;
    const int r16  = lane & 15;
    const int g4   = lane >> 4;

    if (tid < 256) bias[tid] = mbias[tid];
    f32x4 lg = *reinterpret_cast<const f32x4*>(ln_g + lane * 4);
    f32x4 lb = *reinterpret_cast<const f32x4*>(ln_b + lane * 4);

    for (int it = 0; it < 8; ++it) {
        int tt  = wid * 8 + it;
        int tok = tok0 + tt;
        int b_  = tok / NPB, rem = tok - b_ * NPB;
        int h = rem / 112, w = rem - h * 112;
        int hs = h + 3;  if (hs >= 112) hs -= 112;
        int ws_ = w + 3; if (ws_ >= 112) ws_ -= 112;
        const u16* arow = abuf + (size_t)(b_ * NPB + hs * 112 + ws_) * CH;
        ushort4 av = *reinterpret_cast<const ushort4*>(arow + lane * 4);
        f32x4 xv = *reinterpret_cast<const f32x4*>(x + (size_t)tok * CH + lane * 4);
        f32x4 rv;
        rv[0] = xv[0] + bf2f(av.x); rv[1] = xv[1] + bf2f(av.y);
        rv[2] = xv[2] + bf2f(av.z); rv[3] = xv[3] + bf2f(av.w);
        *reinterpret_cast<f32x4*>(&rsd[tt][lane * 4]) = rv;
        float s  = rv[0] + rv[1] + rv[2] + rv[3];
        float sq = rv[0]*rv[0] + rv[1]*rv[1] + rv[2]*rv[2] + rv[3]*rv[3];
        #pragma unroll
        for (int m = 32; m; m >>= 1) { s += __shfl_xor(s, m); sq += __shfl_xor(sq, m); }
        float mu  = s * (1.0f / 256.0f);
        float var = sq * (1.0f / 256.0f) - mu * mu;
        float inv = 1.0f / sqrtf(var + 1e-5f);
        ushort4 o;
        o.x = f2bf((rv[0] - mu) * inv * lg[0] + lb[0]);
        o.y = f2bf((rv[1] - mu) * inv * lg[1] + lb[1]);
        o.z = f2bf((rv[2] - mu) * inv * lg[2] + lb[2]);
        o.w = f2bf((rv[3] - mu) * inv * lg[3] + lb[3]);
        *reinterpret_cast<ushort4*>(&xs[tt][lane * 4]) = o;
    }
    __syncthreads();

    f32x4 acc[4][2];
    #pragma unroll
    for (int i = 0; i < 4; ++i) { acc[i][0] = (f32x4)0.f; acc[i][1] = (f32x4)0.f; }

    #pragma unroll
    for (int kk = 0; kk < 8; ++kk) {
        bfrag b0 = *reinterpret_cast<const bfrag*>(&xs[r16][kk * 32 + g4 * 8]);
        bfrag b1 = *reinterpret_cast<const bfrag*>(&xs[16 + r16][kk * 32 + g4 * 8]);
        #pragma unroll
        for (int ct = 0; ct < 4; ++ct) {
            bfrag wf = *reinterpret_cast<const bfrag*>(wmb + (size_t)(wid * 64 + ct * 16 + r16) * CH + kk * 32 + g4 * 8);
            acc[ct][0] = __builtin_amdgcn_mfma_f32_16x16x32_bf16(wf, b0, acc[ct][0], 0, 0, 0);
            acc[ct][1] = __builtin_amdgcn_mfma_f32_16x16x32_bf16(wf, b1, acc[ct][1], 0, 0, 0);
        }
    }

    #pragma unroll
    for (int ct = 0; ct < 4; ++ct) {
        int ch = wid * 64 + ct * 16 + g4 * 4;
        f32x4 bb = *reinterpret_cast<const f32x4*>(&bias[ch]);
        #pragma unroll
        for (int rt = 0; rt < 2; ++rt) {
            int tokL = rt * 16 + r16;
            f32x4 rb = *reinterpret_cast<const f32x4*>(&rsd[tokL][ch]);
            f32x4 vv;
            #pragma unroll
            for (int rr = 0; rr < 4; ++rr) {
                float val = acc[ct][rt][rr] + bb[rr];
                vv[rr] = 0.5f * val * (1.0f + erff(val * 0.70710678118654752f)) + rb[rr];
            }
            *reinterpret_cast<f32x4*>(out + (size_t)(tok0 + tokL) * CH + ch) = vv;
        }
    }
}

extern "C" void kernel_launch(void* const* d_in, const int* in_sizes, int n_in,
                              void* d_out, int out_size, void* d_ws, size_t ws_size,
                              hipStream_t stream)
{
    const float* x     = (const float*)d_in[0];
    const float* ln_g  = (const float*)d_in[1];
    const float* ln_b  = (const float*)d_in[2];
    const float* wq_w  = (const float*)d_in[3];
    const float* wq_b  = (const float*)d_in[4];
    const float* wk_w  = (const float*)d_in[5];
    const float* wk_b  = (const float*)d_in[6];
    const float* wv_w  = (const float*)d_in[7];
    const float* wv_b  = (const float*)d_in[8];
    const float* mlp_w = (const float*)d_in[9];
    const float* mlp_b = (const float*)d_in[10];

    char* ws = (char*)d_ws;
    u16* wcat = (u16*)ws;                       // 768*256 bf16
    u16* wmb  = (u16*)(ws + 393216);            // 256*256 bf16
    u16* xnq  = (u16*)(ws + 524288);            // xn -> q (in-place) -> attn output
    u16* kbuf = (u16*)d_out;                    // k,v live in d_out until K3 rewrites it
    u16* vbuf = (u16*)d_out + (size_t)NTOK * CH;

    swa_prep <<<256,  256, 0, stream>>>(wq_w, wk_w, wv_w, mlp_w, wcat, wmb);
    swa_ln   <<<1568, 256, 0, stream>>>(x, ln_g, ln_b, xnq);
    swa_qkv7 <<<784,  512, 0, stream>>>(xnq, wcat, wq_b, wk_b, wv_b, xnq, kbuf, vbuf);
    swa_attn <<<3584, 256, 0, stream>>>(xnq, kbuf, vbuf, xnq);
    swa_mlp4 <<<3136, 256, 0, stream>>>(x, xnq, ln_g, ln_b, wmb, mlp_b, (float*)d_out);
}

// Round 9
// 259.247 us; speedup vs baseline: 2.1194x; 1.0894x over previous
//
#include <hip/hip_runtime.h>

#define NTOK 100352   // 8*112*112
#define NPB  12544    // tokens per batch (112*112)
#define CH   256

typedef unsigned short u16;
typedef float f32x4 __attribute__((ext_vector_type(4)));
typedef short bfrag __attribute__((ext_vector_type(8)));   // 8 bf16 = 4 VGPRs

static __device__ __forceinline__ u16 f2bf(float f) {
    union { float f; unsigned u; } v; v.f = f;
    unsigned r = v.u + 0x7FFFu + ((v.u >> 16) & 1u);   // RNE
    return (u16)(r >> 16);
}
static __device__ __forceinline__ float bf2f(u16 h) {
    union { unsigned u; float f; } v; v.u = ((unsigned)h) << 16;
    return v.f;
}
static __device__ __forceinline__ unsigned pk2(float a, float b) {
    return (unsigned)f2bf(a) | ((unsigned)f2bf(b) << 16);
}
// async global->LDS, 16B/lane; LDS dest = wave-uniform base + lane*16 (linear)
static __device__ __forceinline__ void gl16(const u16* g, u16* l) {
    __builtin_amdgcn_global_load_lds(
        (const __attribute__((address_space(1))) void*)g,
        (__attribute__((address_space(3))) void*)l, 16, 0, 0);
}

// ---------------- K0: weight prep (fp32 -> bf16, fold q scale) ----------------
__global__ __launch_bounds__(256)
void swa_prep(const float* __restrict__ wq, const float* __restrict__ wk,
              const float* __restrict__ wv, const float* __restrict__ wm,
              u16* __restrict__ wcat, u16* __restrict__ wmb)
{
    int i0 = blockIdx.x * 256 + threadIdx.x;
    int stride = gridDim.x * 256;
    for (int i = i0; i < 768 * 256; i += stride) {
        int r = i >> 8, c = i & 255;
        float v;
        if (r < 256)      v = wq[r * 256 + c] * 0.0625f;      // fold d^-0.5 = 1/16
        else if (r < 512) v = wk[(r - 256) * 256 + c];
        else              v = wv[(r - 512) * 256 + c];
        wcat[i] = f2bf(v);
    }
    for (int i = i0; i < 256 * 256; i += stride) wmb[i] = f2bf(wm[i]);
}

// ---------------- K1: fused roll+LN+QKV; W-section resident in LDS ----------------
// grid 1176 = 3 sections x 392 strips (sec-major); 512 thr / 8 waves.
// Stage W_sec (256x256 bf16 = 128 KB) ONCE via global_load_lds (pre-swizzled src,
// linear dest); one barrier; then each wave independently computes 32 tokens x 256 ch.
__global__ __launch_bounds__(512)
void swa_qkv8(const float* __restrict__ x,
              const float* __restrict__ ln_g, const float* __restrict__ ln_b,
              const u16* __restrict__ wcat,
              const float* __restrict__ bq, const float* __restrict__ bk,
              const float* __restrict__ bv,
              u16* __restrict__ qbuf, u16* __restrict__ kbuf, u16* __restrict__ vbuf)
{
    __shared__ u16 wt[256 * 256];                 // 128 KB, one section

    const int tid  = threadIdx.x;
    const int lane = tid & 63;
    const int wid  = tid >> 6;
    const int r16  = lane & 15, g4 = lane >> 4;
    const int sec   = blockIdx.x / 392;           // 0=q 1=k 2=v
    const int strip = blockIdx.x % 392;
    const int tok0  = strip * 256 + wid * 32;     // wave's 32 tokens

    // ---- stage W section: 16 rounds x (512 thr x 16B); XOR-swizzle via SOURCE ----
    #pragma unroll
    for (int rr = 0; rr < 16; ++rr) {
        int o   = (tid + rr * 512) * 16;          // linear byte offset in wt
        int row = o >> 9;                         // 512 B per 256-bf16 row
        int cp  = (o >> 4) & 31;                  // 16B chunk within row
        int c   = (cp & 24) | ((cp & 7) ^ (row & 7));
        gl16(wcat + (size_t)(sec * 256 + row) * CH + c * 8, wt + o / 2);
    }

    // ---- roll + LN -> bx (MFMA B-fragments), overlapped with staging ----
    bfrag bx[2][8];
    #pragma unroll
    for (int fj = 0; fj < 2; ++fj) {
        int tok = tok0 + fj * 16 + r16;
        int b_  = tok / NPB, rem = tok - b_ * NPB;
        int h = rem / 112, w = rem - h * 112;
        int h0 = h - 3 + ((h < 3) ? 112 : 0);     // shifted read
        int w0 = w - 3 + ((w < 3) ? 112 : 0);
        const float* rp = x + (size_t)(b_ * NPB + h0 * 112 + w0) * CH + g4 * 8;
        f32x4 xv[16];
        #pragma unroll
        for (int kb = 0; kb < 8; ++kb) {
            xv[kb * 2]     = *reinterpret_cast<const f32x4*>(rp + kb * 32);
            xv[kb * 2 + 1] = *reinterpret_cast<const f32x4*>(rp + kb * 32 + 4);
        }
        float s = 0.f, sq = 0.f;
        #pragma unroll
        for (int q = 0; q < 16; ++q) {
            s  += xv[q][0] + xv[q][1] + xv[q][2] + xv[q][3];
            sq += xv[q][0]*xv[q][0] + xv[q][1]*xv[q][1] + xv[q][2]*xv[q][2] + xv[q][3]*xv[q][3];
        }
        s  += __shfl_xor(s, 16); sq += __shfl_xor(sq, 16);   // reduce over g4 group
        s  += __shfl_xor(s, 32); sq += __shfl_xor(sq, 32);
        float mu  = s * (1.0f / 256.0f);
        float var = sq * (1.0f / 256.0f) - mu * mu;
        float inv = 1.0f / sqrtf(var + 1e-5f);
        #pragma unroll
        for (int kb = 0; kb < 8; ++kb) {
            const float* gp = ln_g + kb * 32 + g4 * 8;
            const float* bp = ln_b + kb * 32 + g4 * 8;
            f32x4 g0 = *reinterpret_cast<const f32x4*>(gp);
            f32x4 g1 = *reinterpret_cast<const f32x4*>(gp + 4);
            f32x4 b0 = *reinterpret_cast<const f32x4*>(bp);
            f32x4 b1 = *reinterpret_cast<const f32x4*>(bp + 4);
            f32x4 a0 = xv[kb * 2], a1 = xv[kb * 2 + 1];
            union { unsigned u[4]; bfrag f; } cv;
            cv.u[0] = pk2((a0[0]-mu)*inv*g0[0]+b0[0], (a0[1]-mu)*inv*g0[1]+b0[1]);
            cv.u[1] = pk2((a0[2]-mu)*inv*g0[2]+b0[2], (a0[3]-mu)*inv*g0[3]+b0[3]);
            cv.u[2] = pk2((a1[0]-mu)*inv*g1[0]+b1[0], (a1[1]-mu)*inv*g1[1]+b1[1]);
            cv.u[3] = pk2((a1[2]-mu)*inv*g1[2]+b1[2], (a1[3]-mu)*inv*g1[3]+b1[3]);
            bx[fj][kb] = cv.f;
        }
    }

    u16*         outp = (sec == 0) ? qbuf : (sec == 1) ? kbuf : vbuf;
    const float* bsp  = (sec == 0) ? bq : (sec == 1) ? bk : bv;
    const float  bsc  = (sec == 0) ? 0.0625f : 1.0f;

    __syncthreads();                              // W staged; only barrier in kernel

    #pragma unroll
    for (int ctg = 0; ctg < 4; ++ctg) {
        f32x4 acc[4][2];
        #pragma unroll
        for (int ct = 0; ct < 4; ++ct) { acc[ct][0] = (f32x4)0.f; acc[ct][1] = (f32x4)0.f; }
        #pragma unroll
        for (int kk = 0; kk < 8; ++kk) {
            bfrag af[4];
            #pragma unroll
            for (int ct = 0; ct < 4; ++ct) {
                int row = ctg * 64 + ct * 16 + r16;
                int cc  = kk * 4 + g4;
                int cp  = (cc & 24) | ((cc & 7) ^ (row & 7));
                af[ct]  = *reinterpret_cast<const bfrag*>((const char*)wt + row * 512 + cp * 16);
            }
            #pragma unroll
            for (int ct = 0; ct < 4; ++ct) {
                acc[ct][0] = __builtin_amdgcn_mfma_f32_16x16x32_bf16(af[ct], bx[0][kk], acc[ct][0], 0, 0, 0);
                acc[ct][1] = __builtin_amdgcn_mfma_f32_16x16x32_bf16(af[ct], bx[1][kk], acc[ct][1], 0, 0, 0);
            }
        }
        #pragma unroll
        for (int ct = 0; ct < 4; ++ct) {
            int ch = ctg * 64 + ct * 16 + g4 * 4;
            f32x4 bb = *reinterpret_cast<const f32x4*>(bsp + ch);
            #pragma unroll
            for (int fj = 0; fj < 2; ++fj) {
                int tok = tok0 + fj * 16 + r16;
                uint2 pkk;
                pkk.x = pk2(acc[ct][fj][0] + bb[0] * bsc, acc[ct][fj][1] + bb[1] * bsc);
                pkk.y = pk2(acc[ct][fj][2] + bb[2] * bsc, acc[ct][fj][3] + bb[3] * bsc);
                *reinterpret_cast<uint2*>(outp + (size_t)tok * CH + ch) = pkk;
            }
        }
    }
}

// ---------------- K2: local attention + on-the-fly k-normalization ----------------
__global__ __launch_bounds__(256)
void swa_attn(const u16* qbuf, const u16* kbuf, const u16* vbuf, u16* obuf)
{
    __shared__ float plds[4][16][17];
    const int tid  = threadIdx.x;
    const int lane = tid & 63;
    const int wid  = tid >> 6;
    const int win  = blockIdx.x * 4 + wid;
    const int iw   = win % 1792;
    const int base = win * 7;
    const int r16  = lane & 15;
    const int g4   = lane >> 4;

    int qrow = base + r16; if (qrow > NTOK - 1) qrow = NTOK - 1;
    int krow = base - 7 + r16; if (krow < 0) krow = 0;
    const u16* qp = qbuf + (size_t)qrow * CH + g4 * 8;
    const u16* kp = kbuf + (size_t)krow * CH + g4 * 8;

    bfrag kf[8];
    #pragma unroll
    for (int kk = 0; kk < 8; ++kk) kf[kk] = *reinterpret_cast<const bfrag*>(kp + kk * 32);
    float sq = 0.f;
    #pragma unroll
    for (int kk = 0; kk < 8; ++kk)
        #pragma unroll
        for (int e = 0; e < 8; ++e) { float kv = bf2f((u16)kf[kk][e]); sq += kv * kv; }
    sq += __shfl_xor(sq, 16); sq += __shfl_xor(sq, 32);
    float invk = 1.0f / fmaxf(sqrtf(sq), 1e-12f);

    f32x4 s4 = {0.f, 0.f, 0.f, 0.f};
    #pragma unroll
    for (int kk = 0; kk < 8; ++kk) {
        bfrag a = *reinterpret_cast<const bfrag*>(qp + kk * 32);
        s4 = __builtin_amdgcn_mfma_f32_16x16x32_bf16(a, kf[kk], s4, 0, 0, 0);
    }

    const int  j     = r16;
    const bool first = (iw == 0);
    #pragma unroll
    for (int rr = 0; rr < 4; ++rr) {
        int i = g4 * 4 + rr;
        float s = s4[rr] * invk;
        if (j == i + 7) s = -5.0e4f;
        if (j > i + 7 || j >= 14 || (first && j < 7)) s = -3.0e38f;
        s4[rr] = s;
    }
    f32x4 mx = s4;
    #pragma unroll
    for (int off = 8; off; off >>= 1) {
        #pragma unroll
        for (int rr = 0; rr < 4; ++rr) mx[rr] = fmaxf(mx[rr], __shfl_xor(mx[rr], off));
    }
    f32x4 p;
    #pragma unroll
    for (int rr = 0; rr < 4; ++rr) p[rr] = __expf(s4[rr] - mx[rr]);
    f32x4 sm = p;
    #pragma unroll
    for (int off = 8; off; off >>= 1) {
        #pragma unroll
        for (int rr = 0; rr < 4; ++rr) sm[rr] += __shfl_xor(sm[rr], off);
    }
    #pragma unroll
    for (int rr = 0; rr < 4; ++rr) plds[wid][g4 * 4 + rr][j] = p[rr] / sm[rr];
    __syncthreads();

    f32x4 zero4 = {0.f, 0.f, 0.f, 0.f};
    f32x4 oa[7];
    #pragma unroll
    for (int i = 0; i < 7; ++i) oa[i] = zero4;
    for (int jj = 0; jj < 14; ++jj) {
        int vrow = base - 7 + jj;
        if (vrow < 0) vrow = 0;
        ushort4 vr = *reinterpret_cast<const ushort4*>(vbuf + (size_t)vrow * CH + lane * 4);
        f32x4 vvv; vvv[0] = bf2f(vr.x); vvv[1] = bf2f(vr.y); vvv[2] = bf2f(vr.z); vvv[3] = bf2f(vr.w);
        #pragma unroll
        for (int i = 0; i < 7; ++i) {
            float pp = plds[wid][i][jj];
            oa[i][0] += pp * vvv[0]; oa[i][1] += pp * vvv[1];
            oa[i][2] += pp * vvv[2]; oa[i][3] += pp * vvv[3];
        }
    }
    #pragma unroll
    for (int i = 0; i < 7; ++i) {
        ushort4 o; o.x = f2bf(oa[i][0]); o.y = f2bf(oa[i][1]); o.z = f2bf(oa[i][2]); o.w = f2bf(oa[i][3]);
        *reinterpret_cast<ushort4*>(obuf + (size_t)(base + i) * CH + lane * 4) = o;
    }
}

// ---------------- K3: unshift + residual + LN + MLP(GELU) + add ----------------
__global__ __launch_bounds__(256)
void swa_mlp4(const float* __restrict__ x, const u16* __restrict__ abuf,
              const float* __restrict__ ln_g, const float* __restrict__ ln_b,
              const u16* __restrict__ wmb, const float* __restrict__ mbias,
              float* __restrict__ out)
{
    __shared__ u16   xs[32][264];
    __shared__ float rsd[32][260];
    __shared__ float bias[256];
    const int tid  = threadIdx.x;
    const int lane = tid & 63;
    const int wid  = tid >> 6;
    const int tok0 = blockIdx.x * 32;
    const int r16  = lane & 15;
    const int g4   = lane >> 4;

    if (tid < 256) bias[tid] = mbias[tid];
    f32x4 lg = *reinterpret_cast<const f32x4*>(ln_g + lane * 4);
    f32x4 lb = *reinterpret_cast<const f32x4*>(ln_b + lane * 4);

    for (int it = 0; it < 8; ++it) {
        int tt  = wid * 8 + it;
        int tok = tok0 + tt;
        int b_  = tok / NPB, rem = tok - b_ * NPB;
        int h = rem / 112, w = rem - h * 112;
        int hs = h + 3;  if (hs >= 112) hs -= 112;
        int ws_ = w + 3; if (ws_ >= 112) ws_ -= 112;
        const u16* arow = abuf + (size_t)(b_ * NPB + hs * 112 + ws_) * CH;
        ushort4 av = *reinterpret_cast<const ushort4*>(arow + lane * 4);
        f32x4 xv = *reinterpret_cast<const f32x4*>(x + (size_t)tok * CH + lane * 4);
        f32x4 rv;
        rv[0] = xv[0] + bf2f(av.x); rv[1] = xv[1] + bf2f(av.y);
        rv[2] = xv[2] + bf2f(av.z); rv[3] = xv[3] + bf2f(av.w);
        *reinterpret_cast<f32x4*>(&rsd[tt][lane * 4]) = rv;
        float s  = rv[0] + rv[1] + rv[2] + rv[3];
        float sq = rv[0]*rv[0] + rv[1]*rv[1] + rv[2]*rv[2] + rv[3]*rv[3];
        #pragma unroll
        for (int m = 32; m; m >>= 1) { s += __shfl_xor(s, m); sq += __shfl_xor(sq, m); }
        float mu  = s * (1.0f / 256.0f);
        float var = sq * (1.0f / 256.0f) - mu * mu;
        float inv = 1.0f / sqrtf(var + 1e-5f);
        ushort4 o;
        o.x = f2bf((rv[0] - mu) * inv * lg[0] + lb[0]);
        o.y = f2bf((rv[1] - mu) * inv * lg[1] + lb[1]);
        o.z = f2bf((rv[2] - mu) * inv * lg[2] + lb[2]);
        o.w = f2bf((rv[3] - mu) * inv * lg[3] + lb[3]);
        *reinterpret_cast<ushort4*>(&xs[tt][lane * 4]) = o;
    }
    __syncthreads();

    f32x4 acc[4][2];
    #pragma unroll
    for (int i = 0; i < 4; ++i) { acc[i][0] = (f32x4)0.f; acc[i][1] = (f32x4)0.f; }

    #pragma unroll
    for (int kk = 0; kk < 8; ++kk) {
        bfrag b0 = *reinterpret_cast<const bfrag*>(&xs[r16][kk * 32 + g4 * 8]);
        bfrag b1 = *reinterpret_cast<const bfrag*>(&xs[16 + r16][kk * 32 + g4 * 8]);
        #pragma unroll
        for (int ct = 0; ct < 4; ++ct) {
            bfrag wf = *reinterpret_cast<const bfrag*>(wmb + (size_t)(wid * 64 + ct * 16 + r16) * CH + kk * 32 + g4 * 8);
            acc[ct][0] = __builtin_amdgcn_mfma_f32_16x16x32_bf16(wf, b0, acc[ct][0], 0, 0, 0);
            acc[ct][1] = __builtin_amdgcn_mfma_f32_16x16x32_bf16(wf, b1, acc[ct][1], 0, 0, 0);
        }
    }

    #pragma unroll
    for (int ct = 0; ct < 4; ++ct) {
        int ch = wid * 64 + ct * 16 + g4 * 4;
        f32x4 bb = *reinterpret_cast<const f32x4*>(&bias[ch]);
        #pragma unroll
        for (int rt = 0; rt < 2; ++rt) {
            int tokL = rt * 16 + r16;
            f32x4 rb = *reinterpret_cast<const f32x4*>(&rsd[tokL][ch]);
            f32x4 vv;
            #pragma unroll
            for (int rr = 0; rr < 4; ++rr) {
                float val = acc[ct][rt][rr] + bb[rr];
                vv[rr] = 0.5f * val * (1.0f + erff(val * 0.70710678118654752f)) + rb[rr];
            }
            *reinterpret_cast<f32x4*>(out + (size_t)(tok0 + tokL) * CH + ch) = vv;
        }
    }
}

extern "C" void kernel_launch(void* const* d_in, const int* in_sizes, int n_in,
                              void* d_out, int out_size, void* d_ws, size_t ws_size,
                              hipStream_t stream)
{
    const float* x     = (const float*)d_in[0];
    const float* ln_g  = (const float*)d_in[1];
    const float* ln_b  = (const float*)d_in[2];
    const float* wq_w  = (const float*)d_in[3];
    const float* wq_b  = (const float*)d_in[4];
    const float* wk_w  = (const float*)d_in[5];
    const float* wk_b  = (const float*)d_in[6];
    const float* wv_w  = (const float*)d_in[7];
    const float* wv_b  = (const float*)d_in[8];
    const float* mlp_w = (const float*)d_in[9];
    const float* mlp_b = (const float*)d_in[10];

    char* ws = (char*)d_ws;
    u16* wcat = (u16*)ws;                       // 768*256 bf16
    u16* wmb  = (u16*)(ws + 393216);            // 256*256 bf16
    u16* qbuf = (u16*)(ws + 524288);            // q; attn output overwrites it
    u16* kbuf = (u16*)d_out;                    // k,v live in d_out until K3 rewrites it
    u16* vbuf = (u16*)d_out + (size_t)NTOK * CH;

    swa_prep <<<256,  256, 0, stream>>>(wq_w, wk_w, wv_w, mlp_w, wcat, wmb);
    swa_qkv8 <<<1176, 512, 0, stream>>>(x, ln_g, ln_b, wcat, wq_b, wk_b, wv_b, qbuf, kbuf, vbuf);
    swa_attn <<<3584, 256, 0, stream>>>(qbuf, kbuf, vbuf, qbuf);
    swa_mlp4 <<<3136, 256, 0, stream>>>(x, qbuf, ln_g, ln_b, wmb, mlp_b, (float*)d_out);
}